// Round 1
// baseline (156.423 us; speedup 1.0000x reference)
//
#include <hip/hip_runtime.h>

typedef unsigned short u16;
typedef unsigned int u32;
typedef unsigned long long u64;
typedef __attribute__((ext_vector_type(8))) short bf16x8;
typedef __attribute__((ext_vector_type(4))) float f32x4;
typedef __attribute__((ext_vector_type(4))) unsigned short u16x4;

// async global->LDS, 16B per lane; LDS dest is wave-uniform base + lane*16
#define GLOAD16(gp, lp)                                                        \
  __builtin_amdgcn_global_load_lds(                                            \
      (__attribute__((address_space(1))) void*)(gp),                           \
      (__attribute__((address_space(3))) void*)(lp), 16, 0, 0)

__device__ __forceinline__ u16 f2bf(float f) {
  u32 u = __builtin_bit_cast(u32, f);
  u += 0x7FFFu + ((u >> 16) & 1u);  // RNE
  return (u16)(u >> 16);
}

__device__ __forceinline__ f32x4 MFMA(bf16x8 a, bf16x8 b, f32x4 c) {
  return __builtin_amdgcn_mfma_f32_16x16x32_bf16(a, b, c, 0, 0, 0);
}

// ---------------------------------------------------------------- kcvt
// fp32 -> bf16 for values/keys/query and the 4 weight matrices.
__global__ __launch_bounds__(256) void kcvt(
    const float* __restrict__ pv, const float* __restrict__ pk,
    const float* __restrict__ pq, const float* __restrict__ pwv,
    const float* __restrict__ pwk, const float* __restrict__ pwq,
    const float* __restrict__ pwu, u16* __restrict__ xv, u16* __restrict__ xk,
    u16* __restrict__ xq, u16* __restrict__ wv, u16* __restrict__ wk,
    u16* __restrict__ wq, u16* __restrict__ wu) {
  int i = blockIdx.x * 256 + threadIdx.x;  // float4 index, 524288 total
  const float* src;
  u16* dst;
  int loc;
  if (i < 131072) {            src = pv;  dst = xv; loc = i; }
  else if (i < 262144) {       src = pk;  dst = xk; loc = i - 131072; }
  else if (i < 393216) {       src = pq;  dst = xq; loc = i - 262144; }
  else if (i < 425984) {       src = pwv; dst = wv; loc = i - 393216; }
  else if (i < 458752) {       src = pwk; dst = wk; loc = i - 425984; }
  else if (i < 491520) {       src = pwq; dst = wq; loc = i - 458752; }
  else {                       src = pwu; dst = wu; loc = i - 491520; }
  f32x4 x = *(const f32x4*)(src + (size_t)loc * 4);
  u16x4 o;
  o[0] = f2bf(x[0]); o[1] = f2bf(x[1]); o[2] = f2bf(x[2]); o[3] = f2bf(x[3]);
  *(u16x4*)(dst + (size_t)loc * 4) = o;
}

// ---------------------------------------------------------------- kmask
// pack mask int32 (B,1,S,S) -> bits pm[b][q][S/64] (u64). One word per wave
// per iter via ballot over 64 consecutive coalesced ints.
__global__ __launch_bounds__(256) void kmask(const int* __restrict__ mask,
                                             u64* __restrict__ pm) {
  int wid = (blockIdx.x * 256 + threadIdx.x) >> 6;  // 0..2047
  int lane = threadIdx.x & 63;
  for (int it = 0; it < 64; ++it) {
    int word = wid * 64 + it;  // 0..131071
    int x = mask[(size_t)word * 64 + lane];
    u64 bits = __ballot(x != 0);
    if (lane == 0) pm[word] = bits;
  }
}

// ---------------------------------------------------------------- kproj
// X(4096x128) @ W(1024x128)^T, bf16 MFMA. z=0: Q (scaled, (b,h,s,d));
// z=1: K ((b,h,s,d)); z=2: V transposed ((b,h,d,s)).
__global__ __launch_bounds__(256) void kproj(
    const u16* __restrict__ Xq, const u16* __restrict__ Xk,
    const u16* __restrict__ Xv, const u16* __restrict__ Wqb,
    const u16* __restrict__ Wkb, const u16* __restrict__ Wvb,
    u16* __restrict__ Qh, u16* __restrict__ Kh, u16* __restrict__ Vt) {
  __shared__ alignas(128) u16 ldsA[128 * 128];  // 32 KB, rows m x 128k
  __shared__ alignas(128) u16 ldsB[64 * 128];   // 16 KB, rows n x 128k
  const int z = blockIdx.z;
  const u16* X = z == 0 ? Xq : (z == 1 ? Xk : Xv);
  const u16* W = z == 0 ? Wqb : (z == 1 ? Wkb : Wvb);
  const int mt = blockIdx.x, nt = blockIdx.y;
  const int tid = threadIdx.x, w = tid >> 6, lane = tid & 63;
  const int lo = lane & 15, hi = lane >> 4;

  // stage A: 32 segs of 1KB; source pre-swizzled (chunk ^= row&7), LDS linear
#pragma unroll
  for (int i = 0; i < 8; i++) {
    int off = (w * 8 + i) * 1024 + lane * 16;
    int r = off >> 8, c = (off >> 4) & 15, g = c ^ (r & 7);
    GLOAD16(X + (size_t)(mt * 128 + r) * 128 + g * 8, (char*)ldsA + off);
  }
  // stage B: 16 segs
#pragma unroll
  for (int i = 0; i < 4; i++) {
    int off = (w * 4 + i) * 1024 + lane * 16;
    int r = off >> 8, c = (off >> 4) & 15, g = c ^ (r & 7);
    GLOAD16(W + (size_t)(nt * 64 + r) * 128 + g * 8, (char*)ldsB + off);
  }
  __syncthreads();

  const int wm = (w >> 1) * 64, wn = (w & 1) * 32;
  f32x4 zero = {0.f, 0.f, 0.f, 0.f};
  f32x4 acc[4][2];
#pragma unroll
  for (int a = 0; a < 4; a++)
#pragma unroll
    for (int b2 = 0; b2 < 2; b2++) acc[a][b2] = zero;

#pragma unroll
  for (int t = 0; t < 4; t++) {
    bf16x8 af[4], bfr[2];
#pragma unroll
    for (int fm = 0; fm < 4; fm++) {
      int r = wm + fm * 16 + lo;
      int ch = (t * 4 + hi) ^ (r & 7);
      af[fm] = *(const bf16x8*)(ldsA + r * 128 + ch * 8);
    }
#pragma unroll
    for (int fn = 0; fn < 2; fn++) {
      int r = wn + fn * 16 + lo;
      int ch = (t * 4 + hi) ^ (r & 7);
      bfr[fn] = *(const bf16x8*)(ldsB + r * 128 + ch * 8);
    }
#pragma unroll
    for (int fm = 0; fm < 4; fm++)
#pragma unroll
      for (int fn = 0; fn < 2; fn++)
        acc[fm][fn] = MFMA(af[fm], bfr[fn], acc[fm][fn]);
  }

  if (z < 2) {
    u16* dst = z == 0 ? Qh : Kh;
    const float scale = z == 0 ? 0.08838834764831845f : 1.0f;  // 1/sqrt(128)
#pragma unroll
    for (int fm = 0; fm < 4; fm++)
#pragma unroll
      for (int fn = 0; fn < 2; fn++) {
        int n = nt * 64 + wn + fn * 16 + lo;
        int h = n >> 7, d = n & 127;
#pragma unroll
        for (int j = 0; j < 4; j++) {
          int m = mt * 128 + wm + fm * 16 + hi * 4 + j;
          int b = m >> 11, s = m & 2047;
          dst[(((size_t)(b * 8 + h) * 2048) + s) * 128 + d] =
              f2bf(acc[fm][fn][j] * scale);
        }
      }
  } else {
#pragma unroll
    for (int fm = 0; fm < 4; fm++)
#pragma unroll
      for (int fn = 0; fn < 2; fn++) {
        int n = nt * 64 + wn + fn * 16 + lo;
        int h = n >> 7, d = n & 127;
        int m0 = mt * 128 + wm + fm * 16 + hi * 4;
        int b = m0 >> 11, s0 = m0 & 2047;  // 4-row block never crosses batch
        u16x4 pk4;
#pragma unroll
        for (int j = 0; j < 4; j++) pk4[j] = f2bf(acc[fm][fn][j]);
        *(u16x4*)(Vt + ((size_t)(b * 8 + h) * 128 + d) * 2048 + s0) = pk4;
      }
  }
}

// ---------------------------------------------------------------- kattn
// flash attention: QBLK=64 (4 waves x 16 q-rows), KBLK=64, online softmax.
__global__ __launch_bounds__(256) void kattn(
    const u16* __restrict__ Qh, const u16* __restrict__ Kh,
    const u16* __restrict__ Vt, const u64* __restrict__ pm,
    u16* __restrict__ AO) {
  __shared__ alignas(128) u16 ldsK[64 * 128];     // 16 KB, row=k_local
  __shared__ alignas(128) u16 ldsV[128 * 64];     // 16 KB, row=d
  __shared__ alignas(128) u16 ldsP[4][16 * 72];   // per-wave P, stride 72
  const int bh = blockIdx.y, b = bh >> 3, h = bh & 7;
  const int tid = threadIdx.x, w = tid >> 6, lane = tid & 63;
  const int lo = lane & 15, hi = lane >> 4;
  const int q0 = blockIdx.x * 64 + w * 16;
  const u16* Qb = Qh + (size_t)bh * 2048 * 128;
  const u16* Kb = Kh + (size_t)bh * 2048 * 128;
  const u16* Vb = Vt + (size_t)bh * 128 * 2048;
  const u64* pmb = pm + (size_t)b * 2048 * 32;

  bf16x8 qa[4];  // Q A-frags, Q pre-scaled by 1/sqrt(128) in kproj
#pragma unroll
  for (int t = 0; t < 4; t++)
    qa[t] = *(const bf16x8*)(Qb + (size_t)(q0 + lo) * 128 + t * 32 + hi * 8);

  f32x4 zero = {0.f, 0.f, 0.f, 0.f};
  f32x4 o[8];
#pragma unroll
  for (int df = 0; df < 8; df++) o[df] = zero;
  float mr[4], lr2[4];
#pragma unroll
  for (int j = 0; j < 4; j++) { mr[j] = -1e30f; lr2[j] = 0.f; }

  for (int kt = 0; kt < 32; ++kt) {
    int k0 = kt * 64;
    // stage K tile (rows 256B, 16 chunks, source chunk ^= row&7)
#pragma unroll
    for (int i = 0; i < 4; i++) {
      int off = (w * 4 + i) * 1024 + lane * 16;
      int r = off >> 8, c = (off >> 4) & 15, g = c ^ (r & 7);
      GLOAD16(Kb + (size_t)(k0 + r) * 128 + g * 8, (char*)ldsK + off);
    }
    // stage V^T tile (rows 128B, 8 chunks)
#pragma unroll
    for (int i = 0; i < 4; i++) {
      int off = (w * 4 + i) * 1024 + lane * 16;
      int d = off >> 7, c = (off >> 4) & 7, g = c ^ (d & 7);
      GLOAD16(Vb + (size_t)d * 2048 + k0 + g * 8, (char*)ldsV + off);
    }
    u64 mw[4];
#pragma unroll
    for (int j = 0; j < 4; j++)
      mw[j] = pmb[(size_t)(q0 + hi * 4 + j) * 32 + kt];
    __syncthreads();

    // S = Q K^T  (C-frag: row q = hi*4+reg, col k = lo)
    f32x4 s[4];
#pragma unroll
    for (int kf = 0; kf < 4; kf++) s[kf] = zero;
#pragma unroll
    for (int kf = 0; kf < 4; kf++)
#pragma unroll
      for (int t = 0; t < 4; t++) {
        int r = kf * 16 + lo;
        int ch = (t * 4 + hi) ^ (r & 7);
        bf16x8 kb = *(const bf16x8*)(ldsK + r * 128 + ch * 8);
        s[kf] = MFMA(qa[t], kb, s[kf]);
      }
    // mask (bit k of word = keep)
#pragma unroll
    for (int j = 0; j < 4; j++) {
      u64 sh = mw[j] >> lo;
#pragma unroll
      for (int kf = 0; kf < 4; kf++)
        if (!((sh >> (kf * 16)) & 1ULL)) s[kf][j] = -1e19f;
    }
    // row max over 64 cols: local over kf, butterfly over 16 lanes
    float px[4], fsc[4], rs[4];
#pragma unroll
    for (int j = 0; j < 4; j++)
      px[j] = fmaxf(fmaxf(s[0][j], s[1][j]), fmaxf(s[2][j], s[3][j]));
#pragma unroll
    for (int msk = 1; msk < 16; msk <<= 1)
#pragma unroll
      for (int j = 0; j < 4; j++)
        px[j] = fmaxf(px[j], __shfl_xor(px[j], msk));
#pragma unroll
    for (int j = 0; j < 4; j++) {
      float mn = fmaxf(mr[j], px[j]);
      fsc[j] = __expf(mr[j] - mn);
      mr[j] = mn;
    }
    // P = exp(S - m), row sums
#pragma unroll
    for (int j = 0; j < 4; j++) {
      float a = 0.f;
#pragma unroll
      for (int kf = 0; kf < 4; kf++) {
        float p = __expf(s[kf][j] - mr[j]);
        s[kf][j] = p;
        a += p;
      }
      rs[j] = a;
    }
#pragma unroll
    for (int msk = 1; msk < 16; msk <<= 1)
#pragma unroll
      for (int j = 0; j < 4; j++) rs[j] += __shfl_xor(rs[j], msk);
#pragma unroll
    for (int j = 0; j < 4; j++) lr2[j] = lr2[j] * fsc[j] + rs[j];
    // rescale O (row map identical to S rows -> lane-local)
#pragma unroll
    for (int df = 0; df < 8; df++)
#pragma unroll
      for (int j = 0; j < 4; j++) o[df][j] *= fsc[j];
    // P -> LDS (per-wave, padded stride 72)
#pragma unroll
    for (int j = 0; j < 4; j++)
#pragma unroll
      for (int kf = 0; kf < 4; kf++)
        ldsP[w][(hi * 4 + j) * 72 + kf * 16 + lo] = f2bf(s[kf][j]);
    // PV: O += P * V
#pragma unroll
    for (int ks = 0; ks < 2; ks++) {
      bf16x8 pa = *(const bf16x8*)(&ldsP[w][lo * 72 + ks * 32 + hi * 8]);
#pragma unroll
      for (int df = 0; df < 8; df++) {
        int dr = df * 16 + lo;
        int ch = (ks * 4 + hi) ^ (dr & 7);
        bf16x8 vb = *(const bf16x8*)(ldsV + dr * 64 + ch * 8);
        o[df] = MFMA(pa, vb, o[df]);
      }
    }
    __syncthreads();
  }
  // epilogue: AO[b][q][h*128+d] = O / l
#pragma unroll
  for (int j = 0; j < 4; j++) {
    float inv = 1.0f / lr2[j];
    int q = q0 + hi * 4 + j;
    size_t base = ((size_t)(b * 2048 + q)) * 1024 + h * 128;
#pragma unroll
    for (int df = 0; df < 8; df++)
      AO[base + df * 16 + lo] = f2bf(o[df][j] * inv);
  }
}

// ---------------------------------------------------------------- kout
// AO(4096x1024) @ Wu(128x1024)^T + bu -> fp32 out (4096x128)
__global__ __launch_bounds__(256) void kout(const u16* __restrict__ AO,
                                            const u16* __restrict__ Wub,
                                            const float* __restrict__ bu,
                                            float* __restrict__ out) {
  __shared__ alignas(128) u16 ldsA[64 * 128];    // 16 KB
  __shared__ alignas(128) u16 ldsW[128 * 128];   // 32 KB
  const int mt = blockIdx.x;
  const int tid = threadIdx.x, w = tid >> 6, lane = tid & 63;
  const int lo = lane & 15, hi = lane >> 4;
  f32x4 zero = {0.f, 0.f, 0.f, 0.f};
  f32x4 acc[8];
#pragma unroll
  for (int fn = 0; fn < 8; fn++) acc[fn] = zero;

  for (int kb = 0; kb < 8; ++kb) {
    int k0 = kb * 128;
#pragma unroll
    for (int i = 0; i < 4; i++) {
      int off = (w * 4 + i) * 1024 + lane * 16;
      int r = off >> 8, c = (off >> 4) & 15, g = c ^ (r & 7);
      GLOAD16(AO + (size_t)(mt * 64 + r) * 1024 + k0 + g * 8, (char*)ldsA + off);
    }
#pragma unroll
    for (int i = 0; i < 8; i++) {
      int off = (w * 8 + i) * 1024 + lane * 16;
      int r = off >> 8, c = (off >> 4) & 15, g = c ^ (r & 7);
      GLOAD16(Wub + (size_t)r * 1024 + k0 + g * 8, (char*)ldsW + off);
    }
    __syncthreads();
#pragma unroll
    for (int t = 0; t < 4; t++) {
      int ra = w * 16 + lo, cha = (t * 4 + hi) ^ (ra & 7);
      bf16x8 af = *(const bf16x8*)(ldsA + ra * 128 + cha * 8);
#pragma unroll
      for (int fn = 0; fn < 8; fn++) {
        int rb = fn * 16 + lo, chb = (t * 4 + hi) ^ (rb & 7);
        bf16x8 bf_ = *(const bf16x8*)(ldsW + rb * 128 + chb * 8);
        acc[fn] = MFMA(af, bf_, acc[fn]);
      }
    }
    __syncthreads();
  }
#pragma unroll
  for (int fn = 0; fn < 8; fn++) {
    int n = fn * 16 + lo;
    float bias = bu[n];
#pragma unroll
    for (int j = 0; j < 4; j++) {
      int m = mt * 64 + w * 16 + hi * 4 + j;
      out[(size_t)m * 128 + n] = acc[fn][j] + bias;
    }
  }
}

// ---------------------------------------------------------------- launch
extern "C" void kernel_launch(void* const* d_in, const int* in_sizes, int n_in,
                              void* d_out, int out_size, void* d_ws,
                              size_t ws_size, hipStream_t stream) {
  const float* values = (const float*)d_in[0];
  const float* keys = (const float*)d_in[1];
  const float* query = (const float*)d_in[2];
  const int* mask = (const int*)d_in[3];
  const float* Wv = (const float*)d_in[4];
  const float* Wk = (const float*)d_in[5];
  const float* Wq = (const float*)d_in[6];
  const float* Wu = (const float*)d_in[7];
  const float* bu = (const float*)d_in[8];

  char* ws = (char*)d_ws;
  u16* XV = (u16*)(ws + 0);          // values bf16          1 MB
  u16* XK = (u16*)(ws + 1048576);    // keys bf16
  u16* XQ = (u16*)(ws + 2097152);    // query bf16
  u16* WVB = (u16*)(ws + 3145728);   // weights bf16, 256 KB each
  u16* WKB = (u16*)(ws + 3407872);
  u16* WQB = (u16*)(ws + 3670016);
  u16* WUB = (u16*)(ws + 3932160);
  u16* QH = (u16*)(ws + 4194304);    // (b,h,s,d) scaled     8 MB
  u16* KH = (u16*)(ws + 12582912);   // (b,h,s,d)
  u16* VT = (u16*)(ws + 20971520);   // (b,h,d,s)
  u16* AO = (u16*)(ws + 29360128);   // (b,q,h,d)
  u64* PM = (u64*)(ws + 37748736);   // packed mask          1 MB
  // total ws use: 38797312 bytes

  kcvt<<<2048, 256, 0, stream>>>(values, keys, query, Wv, Wk, Wq, Wu, XV, XK,
                                 XQ, WVB, WKB, WQB, WUB);
  kmask<<<512, 256, 0, stream>>>(mask, PM);
  kproj<<<dim3(32, 16, 3), 256, 0, stream>>>(XQ, XK, XV, WQB, WKB, WVB, QH, KH,
                                             VT);
  kattn<<<dim3(32, 16), 256, 0, stream>>>(QH, KH, VT, PM, AO);
  kout<<<64, 256, 0, stream>>>(AO, WUB, bu, (float*)d_out);
}

// Round 2
// 140.958 us; speedup vs baseline: 1.1097x; 1.1097x over previous
//
#include <hip/hip_runtime.h>

typedef unsigned short u16;
typedef unsigned int u32;
typedef unsigned long long u64;
typedef __attribute__((ext_vector_type(8))) short bf16x8;
typedef __attribute__((ext_vector_type(4))) float f32x4;
typedef __attribute__((ext_vector_type(4))) unsigned short u16x4;

// async global->LDS, 16B per lane; LDS dest is wave-uniform base + lane*16
#define GLOAD16(gp, lp)                                                        \
  __builtin_amdgcn_global_load_lds(                                            \
      (__attribute__((address_space(1))) void*)(gp),                           \
      (__attribute__((address_space(3))) void*)(lp), 16, 0, 0)

#if __has_builtin(__builtin_amdgcn_exp2f)
#define EXP2(x) __builtin_amdgcn_exp2f(x)
#else
#define EXP2(x) __expf(0.6931471805599453f * (x))
#endif

__device__ __forceinline__ u16 f2bf(float f) {
  u32 u = __builtin_bit_cast(u32, f);
  u += 0x7FFFu + ((u >> 16) & 1u);  // RNE
  return (u16)(u >> 16);
}

__device__ __forceinline__ f32x4 MFMA(bf16x8 a, bf16x8 b, f32x4 c) {
  return __builtin_amdgcn_mfma_f32_16x16x32_bf16(a, b, c, 0, 0, 0);
}

// ---------------------------------------------------------------- kprep
// blocks [0,2048): fp32->bf16 convert of v/k/q + 4 weights (float4 granules).
// blocks [2048,2560): bit-pack mask via ballot: 64 ints -> one u64.
__global__ __launch_bounds__(256) void kprep(
    const float* __restrict__ pv, const float* __restrict__ pk,
    const float* __restrict__ pq, const float* __restrict__ pwv,
    const float* __restrict__ pwk, const float* __restrict__ pwq,
    const float* __restrict__ pwu, const int* __restrict__ mask,
    u16* __restrict__ xv, u16* __restrict__ xk, u16* __restrict__ xq,
    u16* __restrict__ wv, u16* __restrict__ wk, u16* __restrict__ wq,
    u16* __restrict__ wu, u64* __restrict__ pm) {
  int blk = blockIdx.x;
  if (blk < 2048) {
    int i = blk * 256 + threadIdx.x;  // float4 index, 524288 total
    const float* src;
    u16* dst;
    int loc;
    if (i < 131072) {            src = pv;  dst = xv; loc = i; }
    else if (i < 262144) {       src = pk;  dst = xk; loc = i - 131072; }
    else if (i < 393216) {       src = pq;  dst = xq; loc = i - 262144; }
    else if (i < 425984) {       src = pwv; dst = wv; loc = i - 393216; }
    else if (i < 458752) {       src = pwk; dst = wk; loc = i - 425984; }
    else if (i < 491520) {       src = pwq; dst = wq; loc = i - 458752; }
    else {                       src = pwu; dst = wu; loc = i - 491520; }
    f32x4 x = *(const f32x4*)(src + (size_t)loc * 4);
    u16x4 o;
    o[0] = f2bf(x[0]); o[1] = f2bf(x[1]); o[2] = f2bf(x[2]); o[3] = f2bf(x[3]);
    *(u16x4*)(dst + (size_t)loc * 4) = o;
  } else {
    int wid = ((blk - 2048) * 256 + threadIdx.x) >> 6;  // 0..2047
    int lane = threadIdx.x & 63;
    for (int it = 0; it < 64; ++it) {
      int word = wid * 64 + it;  // 0..131071
      int x = mask[(size_t)word * 64 + lane];
      u64 bits = __ballot(x != 0);
      if (lane == 0) pm[word] = bits;
    }
  }
}

// ---------------------------------------------------------------- kproj
// X(4096x128) @ W(1024x128)^T, bf16 MFMA. z=0: Q (scaled by 1/(sqrt(128)ln2),
// (b,h,s,d)); z=1: K ((b,h,s,d)); z=2: V transposed ((b,h,d,s)).
__global__ __launch_bounds__(256) void kproj(
    const u16* __restrict__ Xq, const u16* __restrict__ Xk,
    const u16* __restrict__ Xv, const u16* __restrict__ Wqb,
    const u16* __restrict__ Wkb, const u16* __restrict__ Wvb,
    u16* __restrict__ Qh, u16* __restrict__ Kh, u16* __restrict__ Vt) {
  __shared__ alignas(128) u16 ldsA[128 * 128];  // 32 KB
  __shared__ alignas(128) u16 ldsB[64 * 128];   // 16 KB
  const int z = blockIdx.z;
  const u16* X = z == 0 ? Xq : (z == 1 ? Xk : Xv);
  const u16* W = z == 0 ? Wqb : (z == 1 ? Wkb : Wvb);
  const int mt = blockIdx.x, nt = blockIdx.y;
  const int tid = threadIdx.x, w = tid >> 6, lane = tid & 63;
  const int lo = lane & 15, hi = lane >> 4;

#pragma unroll
  for (int i = 0; i < 8; i++) {
    int off = (w * 8 + i) * 1024 + lane * 16;
    int r = off >> 8, c = (off >> 4) & 15, g = c ^ (r & 7);
    GLOAD16(X + (size_t)(mt * 128 + r) * 128 + g * 8, (char*)ldsA + off);
  }
#pragma unroll
  for (int i = 0; i < 4; i++) {
    int off = (w * 4 + i) * 1024 + lane * 16;
    int r = off >> 8, c = (off >> 4) & 15, g = c ^ (r & 7);
    GLOAD16(W + (size_t)(nt * 64 + r) * 128 + g * 8, (char*)ldsB + off);
  }
  __syncthreads();

  const int wm = (w >> 1) * 64, wn = (w & 1) * 32;
  f32x4 zero = {0.f, 0.f, 0.f, 0.f};
  f32x4 acc[4][2];
#pragma unroll
  for (int a = 0; a < 4; a++)
#pragma unroll
    for (int b2 = 0; b2 < 2; b2++) acc[a][b2] = zero;

#pragma unroll
  for (int t = 0; t < 4; t++) {
    bf16x8 af[4], bfr[2];
#pragma unroll
    for (int fm = 0; fm < 4; fm++) {
      int r = wm + fm * 16 + lo;
      int ch = (t * 4 + hi) ^ (r & 7);
      af[fm] = *(const bf16x8*)(ldsA + r * 128 + ch * 8);
    }
#pragma unroll
    for (int fn = 0; fn < 2; fn++) {
      int r = wn + fn * 16 + lo;
      int ch = (t * 4 + hi) ^ (r & 7);
      bfr[fn] = *(const bf16x8*)(ldsB + r * 128 + ch * 8);
    }
#pragma unroll
    for (int fm = 0; fm < 4; fm++)
#pragma unroll
      for (int fn = 0; fn < 2; fn++)
        acc[fm][fn] = MFMA(af[fm], bfr[fn], acc[fm][fn]);
  }

  if (z < 2) {
    u16* dst = z == 0 ? Qh : Kh;
    // Q scale folds 1/sqrt(128) and 1/ln2 (softmax runs in exp2 units)
    const float scale = z == 0 ? 0.12753103392461437f : 1.0f;
#pragma unroll
    for (int fm = 0; fm < 4; fm++)
#pragma unroll
      for (int fn = 0; fn < 2; fn++) {
        int n = nt * 64 + wn + fn * 16 + lo;
        int h = n >> 7, d = n & 127;
#pragma unroll
        for (int j = 0; j < 4; j++) {
          int m = mt * 128 + wm + fm * 16 + hi * 4 + j;
          int b = m >> 11, s = m & 2047;
          dst[(((size_t)(b * 8 + h) * 2048) + s) * 128 + d] =
              f2bf(acc[fm][fn][j] * scale);
        }
      }
  } else {
#pragma unroll
    for (int fm = 0; fm < 4; fm++)
#pragma unroll
      for (int fn = 0; fn < 2; fn++) {
        int n = nt * 64 + wn + fn * 16 + lo;
        int h = n >> 7, d = n & 127;
        int m0 = mt * 128 + wm + fm * 16 + hi * 4;
        int b = m0 >> 11, s0 = m0 & 2047;
        u16x4 pk4;
#pragma unroll
        for (int j = 0; j < 4; j++) pk4[j] = f2bf(acc[fm][fn][j]);
        *(u16x4*)(Vt + ((size_t)(b * 8 + h) * 128 + d) * 2048 + s0) = pk4;
      }
  }
}

// ---------------------------------------------------------------- kattn
// flash attention, 2-phase double-buffered K/V pipeline, one barrier/tile.
__global__ __launch_bounds__(256) void kattn(
    const u16* __restrict__ Qh, const u16* __restrict__ Kh,
    const u16* __restrict__ Vt, const u64* __restrict__ pm,
    u16* __restrict__ AO) {
  __shared__ alignas(128) u16 ldsK[2][64 * 128];   // 2 x 16 KB, row=k_local
  __shared__ alignas(128) u16 ldsV[2][128 * 64];   // 2 x 16 KB, row=d
  __shared__ alignas(128) u16 ldsP[4][16 * 72];    // per-wave P, stride 72
  const int bh = blockIdx.y, b = bh >> 3, h = bh & 7;
  const int tid = threadIdx.x, w = tid >> 6, lane = tid & 63;
  const int lo = lane & 15, hi = lane >> 4;
  const int q0 = blockIdx.x * 64 + w * 16;
  const u16* Qb = Qh + (size_t)bh * 2048 * 128;
  const u16* Kb = Kh + (size_t)bh * 2048 * 128;
  const u16* Vb = Vt + (size_t)bh * 128 * 2048;
  const u64* pmb = pm + (size_t)b * 2048 * 32;

  bf16x8 qa[4];  // Q A-frags, pre-scaled in kproj
#pragma unroll
  for (int t = 0; t < 4; t++)
    qa[t] = *(const bf16x8*)(Qb + (size_t)(q0 + lo) * 128 + t * 32 + hi * 8);

  f32x4 zero = {0.f, 0.f, 0.f, 0.f};
  f32x4 o[8];
#pragma unroll
  for (int df = 0; df < 8; df++) o[df] = zero;
  float mr[4], lr2[4];
#pragma unroll
  for (int j = 0; j < 4; j++) { mr[j] = -1e30f; lr2[j] = 0.f; }

  u64 mwc[4], mwn[4];

#define STAGE(kt, bb)                                                          \
  do {                                                                         \
    int k0_ = (kt) * 64;                                                       \
    _Pragma("unroll") for (int i = 0; i < 4; i++) {                            \
      int off = (w * 4 + i) * 1024 + lane * 16;                                \
      int r = off >> 8, c = (off >> 4) & 15, g = c ^ (r & 7);                  \
      GLOAD16(Kb + (size_t)(k0_ + r) * 128 + g * 8, (char*)ldsK[bb] + off);    \
    }                                                                          \
    _Pragma("unroll") for (int i = 0; i < 4; i++) {                            \
      int off = (w * 4 + i) * 1024 + lane * 16;                                \
      int d = off >> 7, c = (off >> 4) & 7, g = c ^ (d & 7);                   \
      GLOAD16(Vb + (size_t)d * 2048 + k0_ + g * 8, (char*)ldsV[bb] + off);     \
    }                                                                          \
  } while (0)

#define LOADM(kt, mw)                                                          \
  do {                                                                         \
    _Pragma("unroll") for (int j = 0; j < 4; j++)                              \
        mw[j] = pmb[(size_t)(q0 + hi * 4 + j) * 32 + (kt)];                    \
  } while (0)

  STAGE(0, 0);
  LOADM(0, mwc);
  __syncthreads();

  for (int kt = 0; kt < 32; ++kt) {
    const int cb = kt & 1;
    if (kt < 31) {          // prefetch next tile while computing this one
      STAGE(kt + 1, cb ^ 1);
      LOADM(kt + 1, mwn);
    }

    // S = Q K^T  (C-frag: row q = hi*4+j, col k = lo)
    f32x4 s[4];
#pragma unroll
    for (int kf = 0; kf < 4; kf++) s[kf] = zero;
    __builtin_amdgcn_s_setprio(1);
#pragma unroll
    for (int kf = 0; kf < 4; kf++)
#pragma unroll
      for (int t = 0; t < 4; t++) {
        int r = kf * 16 + lo;
        int ch = (t * 4 + hi) ^ (r & 7);
        bf16x8 kb = *(const bf16x8*)(ldsK[cb] + r * 128 + ch * 8);
        s[kf] = MFMA(qa[t], kb, s[kf]);
      }
    __builtin_amdgcn_s_setprio(0);

    // mask (bit k of word = keep)
#pragma unroll
    for (int j = 0; j < 4; j++) {
      u64 sh = mwc[j] >> lo;
#pragma unroll
      for (int kf = 0; kf < 4; kf++)
        if (!((sh >> (kf * 16)) & 1ULL)) s[kf][j] = -1e19f;
    }
    // row max: local over kf, butterfly over 16 lanes
    float px[4], fsc[4], rs[4];
#pragma unroll
    for (int j = 0; j < 4; j++)
      px[j] = fmaxf(fmaxf(s[0][j], s[1][j]), fmaxf(s[2][j], s[3][j]));
#pragma unroll
    for (int msk = 1; msk < 16; msk <<= 1)
#pragma unroll
      for (int j = 0; j < 4; j++)
        px[j] = fmaxf(px[j], __shfl_xor(px[j], msk));
#pragma unroll
    for (int j = 0; j < 4; j++) {
      float mn = fmaxf(mr[j], px[j]);
      fsc[j] = EXP2(mr[j] - mn);
      mr[j] = mn;
    }
    // P = exp2(S - m), row sums
#pragma unroll
    for (int j = 0; j < 4; j++) {
      float a = 0.f;
#pragma unroll
      for (int kf = 0; kf < 4; kf++) {
        float p = EXP2(s[kf][j] - mr[j]);
        s[kf][j] = p;
        a += p;
      }
      rs[j] = a;
    }
#pragma unroll
    for (int msk = 1; msk < 16; msk <<= 1)
#pragma unroll
      for (int j = 0; j < 4; j++) rs[j] += __shfl_xor(rs[j], msk);
#pragma unroll
    for (int j = 0; j < 4; j++) lr2[j] = lr2[j] * fsc[j] + rs[j];
    // rescale O (row map identical to S rows -> lane-local)
#pragma unroll
    for (int df = 0; df < 8; df++)
#pragma unroll
      for (int j = 0; j < 4; j++) o[df][j] *= fsc[j];
    // P -> LDS (per-wave, padded stride 72)
#pragma unroll
    for (int j = 0; j < 4; j++)
#pragma unroll
      for (int kf = 0; kf < 4; kf++)
        ldsP[w][(hi * 4 + j) * 72 + kf * 16 + lo] = f2bf(s[kf][j]);
    // PV: O += P * V
    __builtin_amdgcn_s_setprio(1);
#pragma unroll
    for (int ks = 0; ks < 2; ks++) {
      bf16x8 pa = *(const bf16x8*)(&ldsP[w][lo * 72 + ks * 32 + hi * 8]);
#pragma unroll
      for (int df = 0; df < 8; df++) {
        int dr = df * 16 + lo;
        int ch = (ks * 4 + hi) ^ (dr & 7);
        bf16x8 vb = *(const bf16x8*)(ldsV[cb] + dr * 64 + ch * 8);
        o[df] = MFMA(pa, vb, o[df]);
      }
    }
    __builtin_amdgcn_s_setprio(0);

#pragma unroll
    for (int j = 0; j < 4; j++) mwc[j] = mwn[j];
    __syncthreads();
  }
#undef STAGE
#undef LOADM

  // epilogue: AO[b][q][h*128+d] = O / l
#pragma unroll
  for (int j = 0; j < 4; j++) {
    float inv = 1.0f / lr2[j];
    int q = q0 + hi * 4 + j;
    size_t base = ((size_t)(b * 2048 + q)) * 1024 + h * 128;
#pragma unroll
    for (int df = 0; df < 8; df++)
      AO[base + df * 16 + lo] = f2bf(o[df][j] * inv);
  }
}

// ---------------------------------------------------------------- kout
// AO(4096x1024) @ Wu(128x1024)^T + bu -> fp32 out (4096x128), 2-phase dbuf.
__global__ __launch_bounds__(256) void kout(const u16* __restrict__ AO,
                                            const u16* __restrict__ Wub,
                                            const float* __restrict__ bu,
                                            float* __restrict__ out) {
  __shared__ alignas(128) u16 ldsA[2][64 * 128];    // 2 x 16 KB
  __shared__ alignas(128) u16 ldsW[2][128 * 128];   // 2 x 32 KB
  const int mt = blockIdx.x;
  const int tid = threadIdx.x, w = tid >> 6, lane = tid & 63;
  const int lo = lane & 15, hi = lane >> 4;
  f32x4 zero = {0.f, 0.f, 0.f, 0.f};
  f32x4 acc[8];
#pragma unroll
  for (int fn = 0; fn < 8; fn++) acc[fn] = zero;

#define STAGEO(kb, bb)                                                         \
  do {                                                                         \
    int k0_ = (kb) * 128;                                                      \
    _Pragma("unroll") for (int i = 0; i < 4; i++) {                            \
      int off = (w * 4 + i) * 1024 + lane * 16;                                \
      int r = off >> 8, c = (off >> 4) & 15, g = c ^ (r & 7);                  \
      GLOAD16(AO + (size_t)(mt * 64 + r) * 1024 + k0_ + g * 8,                 \
              (char*)ldsA[bb] + off);                                          \
    }                                                                          \
    _Pragma("unroll") for (int i = 0; i < 8; i++) {                            \
      int off = (w * 8 + i) * 1024 + lane * 16;                                \
      int r = off >> 8, c = (off >> 4) & 15, g = c ^ (r & 7);                  \
      GLOAD16(Wub + (size_t)r * 1024 + k0_ + g * 8, (char*)ldsW[bb] + off);    \
    }                                                                          \
  } while (0)

  STAGEO(0, 0);
  __syncthreads();
  for (int kb = 0; kb < 8; ++kb) {
    const int cb = kb & 1;
    if (kb < 7) STAGEO(kb + 1, cb ^ 1);
    __builtin_amdgcn_s_setprio(1);
#pragma unroll
    for (int t = 0; t < 4; t++) {
      int ra = w * 16 + lo, cha = (t * 4 + hi) ^ (ra & 7);
      bf16x8 af = *(const bf16x8*)(ldsA[cb] + ra * 128 + cha * 8);
#pragma unroll
      for (int fn = 0; fn < 8; fn++) {
        int rb = fn * 16 + lo, chb = (t * 4 + hi) ^ (rb & 7);
        bf16x8 bf_ = *(const bf16x8*)(ldsW[cb] + rb * 128 + chb * 8);
        acc[fn] = MFMA(af, bf_, acc[fn]);
      }
    }
    __builtin_amdgcn_s_setprio(0);
    __syncthreads();
  }
#undef STAGEO

#pragma unroll
  for (int fn = 0; fn < 8; fn++) {
    int n = fn * 16 + lo;
    float bias = bu[n];
#pragma unroll
    for (int j = 0; j < 4; j++) {
      int m = mt * 64 + w * 16 + hi * 4 + j;
      out[(size_t)m * 128 + n] = acc[fn][j] + bias;
    }
  }
}

// ---------------------------------------------------------------- launch
extern "C" void kernel_launch(void* const* d_in, const int* in_sizes, int n_in,
                              void* d_out, int out_size, void* d_ws,
                              size_t ws_size, hipStream_t stream) {
  const float* values = (const float*)d_in[0];
  const float* keys = (const float*)d_in[1];
  const float* query = (const float*)d_in[2];
  const int* mask = (const int*)d_in[3];
  const float* Wv = (const float*)d_in[4];
  const float* Wk = (const float*)d_in[5];
  const float* Wq = (const float*)d_in[6];
  const float* Wu = (const float*)d_in[7];
  const float* bu = (const float*)d_in[8];

  char* ws = (char*)d_ws;
  u16* XV = (u16*)(ws + 0);          // values bf16          1 MB
  u16* XK = (u16*)(ws + 1048576);    // keys bf16
  u16* XQ = (u16*)(ws + 2097152);    // query bf16
  u16* WVB = (u16*)(ws + 3145728);   // weights bf16, 256 KB each
  u16* WKB = (u16*)(ws + 3407872);
  u16* WQB = (u16*)(ws + 3670016);
  u16* WUB = (u16*)(ws + 3932160);
  u16* QH = (u16*)(ws + 4194304);    // (b,h,s,d) scaled     8 MB
  u16* KH = (u16*)(ws + 12582912);   // (b,h,s,d)
  u16* VT = (u16*)(ws + 20971520);   // (b,h,d,s)
  u16* AO = (u16*)(ws + 29360128);   // (b,q,h,d)
  u64* PM = (u64*)(ws + 37748736);   // packed mask          1 MB

  kprep<<<2560, 256, 0, stream>>>(values, keys, query, Wv, Wk, Wq, Wu, mask,
                                  XV, XK, XQ, WVB, WKB, WQB, WUB, PM);
  kproj<<<dim3(32, 16, 3), 256, 0, stream>>>(XQ, XK, XV, WQB, WKB, WVB, QH, KH,
                                             VT);
  kattn<<<dim3(32, 16), 256, 0, stream>>>(QH, KH, VT, PM, AO);
  kout<<<64, 256, 0, stream>>>(AO, WUB, bu, (float*)d_out);
}

// Round 3
// 129.991 us; speedup vs baseline: 1.2033x; 1.0844x over previous
//
#include <hip/hip_runtime.h>

typedef unsigned short u16;
typedef unsigned int u32;
typedef unsigned long long u64;
typedef __attribute__((ext_vector_type(8))) short bf16x8;
typedef __attribute__((ext_vector_type(4))) float f32x4;
typedef __attribute__((ext_vector_type(16))) float f32x16;
typedef __attribute__((ext_vector_type(4))) u32 u32x4;
typedef __attribute__((ext_vector_type(4))) unsigned short u16x4;

// async global->LDS, 16B per lane; LDS dest is wave-uniform base + lane*16
#define GLOAD16(gp, lp)                                                        \
  __builtin_amdgcn_global_load_lds(                                            \
      (__attribute__((address_space(1))) void*)(gp),                           \
      (__attribute__((address_space(3))) void*)(lp), 16, 0, 0)

#if __has_builtin(__builtin_amdgcn_exp2f)
#define EXP2(x) __builtin_amdgcn_exp2f(x)
#else
#define EXP2(x) __expf(0.6931471805599453f * (x))
#endif

#define Z16                                                                    \
  { 0.f, 0.f, 0.f, 0.f, 0.f, 0.f, 0.f, 0.f, 0.f, 0.f, 0.f, 0.f, 0.f, 0.f,     \
    0.f, 0.f }

__device__ __forceinline__ u16 f2bf(float f) {
  u32 u = __builtin_bit_cast(u32, f);
  u += 0x7FFFu + ((u >> 16) & 1u);  // RNE
  return (u16)(u >> 16);
}

__device__ __forceinline__ u32 cvtpk(float lo, float hi) {
  u32 r;
  asm("v_cvt_pk_bf16_f32 %0, %1, %2" : "=v"(r) : "v"(lo), "v"(hi));
  return r;
}

// exchanges a's lanes 32-63 with b's lanes 0-31
__device__ __forceinline__ void plswap(u32& a, u32& b) {
  asm volatile("v_permlane32_swap_b32 %0, %1" : "+v"(a), "+v"(b));
}

__device__ __forceinline__ f32x4 MFMA(bf16x8 a, bf16x8 b, f32x4 c) {
  return __builtin_amdgcn_mfma_f32_16x16x32_bf16(a, b, c, 0, 0, 0);
}
__device__ __forceinline__ f32x16 MFMA32(bf16x8 a, bf16x8 b, f32x16 c) {
  return __builtin_amdgcn_mfma_f32_32x32x16_bf16(a, b, c, 0, 0, 0);
}

// ---------------------------------------------------------------- kprep
// blocks [0,2048): fp32->bf16 convert of v/k/q + 4 weights (float4 granules).
// blocks [2048,2560): bit-pack mask via ballot: 64 ints -> one u64.
__global__ __launch_bounds__(256) void kprep(
    const float* __restrict__ pv, const float* __restrict__ pk,
    const float* __restrict__ pq, const float* __restrict__ pwv,
    const float* __restrict__ pwk, const float* __restrict__ pwq,
    const float* __restrict__ pwu, const int* __restrict__ mask,
    u16* __restrict__ xv, u16* __restrict__ xk, u16* __restrict__ xq,
    u16* __restrict__ wv, u16* __restrict__ wk, u16* __restrict__ wq,
    u16* __restrict__ wu, u64* __restrict__ pm) {
  int blk = blockIdx.x;
  if (blk < 2048) {
    int i = blk * 256 + threadIdx.x;  // float4 index, 524288 total
    const float* src;
    u16* dst;
    int loc;
    if (i < 131072) {            src = pv;  dst = xv; loc = i; }
    else if (i < 262144) {       src = pk;  dst = xk; loc = i - 131072; }
    else if (i < 393216) {       src = pq;  dst = xq; loc = i - 262144; }
    else if (i < 425984) {       src = pwv; dst = wv; loc = i - 393216; }
    else if (i < 458752) {       src = pwk; dst = wk; loc = i - 425984; }
    else if (i < 491520) {       src = pwq; dst = wq; loc = i - 458752; }
    else {                       src = pwu; dst = wu; loc = i - 491520; }
    f32x4 x = *(const f32x4*)(src + (size_t)loc * 4);
    u16x4 o;
    o[0] = f2bf(x[0]); o[1] = f2bf(x[1]); o[2] = f2bf(x[2]); o[3] = f2bf(x[3]);
    *(u16x4*)(dst + (size_t)loc * 4) = o;
  } else {
    int wid = ((blk - 2048) * 256 + threadIdx.x) >> 6;  // 0..2047
    int lane = threadIdx.x & 63;
    for (int it = 0; it < 64; ++it) {
      int word = wid * 64 + it;  // 0..131071
      int x = mask[(size_t)word * 64 + lane];
      u64 bits = __ballot(x != 0);
      if (lane == 0) pm[word] = bits;
    }
  }
}

// ---------------------------------------------------------------- kproj
// X(4096x128) @ W(1024x128)^T, bf16 MFMA. z=0: Q (scaled by 1/(sqrt(128)ln2),
// (b,h,s,d)); z=1: K ((b,h,s,d)); z=2: V transposed ((b,h,d,s)).
__global__ __launch_bounds__(256) void kproj(
    const u16* __restrict__ Xq, const u16* __restrict__ Xk,
    const u16* __restrict__ Xv, const u16* __restrict__ Wqb,
    const u16* __restrict__ Wkb, const u16* __restrict__ Wvb,
    u16* __restrict__ Qh, u16* __restrict__ Kh, u16* __restrict__ Vt) {
  __shared__ alignas(128) u16 ldsA[128 * 128];  // 32 KB
  __shared__ alignas(128) u16 ldsB[64 * 128];   // 16 KB
  const int z = blockIdx.z;
  const u16* X = z == 0 ? Xq : (z == 1 ? Xk : Xv);
  const u16* W = z == 0 ? Wqb : (z == 1 ? Wkb : Wvb);
  const int mt = blockIdx.x, nt = blockIdx.y;
  const int tid = threadIdx.x, w = tid >> 6, lane = tid & 63;
  const int lo = lane & 15, hi = lane >> 4;

#pragma unroll
  for (int i = 0; i < 8; i++) {
    int off = (w * 8 + i) * 1024 + lane * 16;
    int r = off >> 8, c = (off >> 4) & 15, g = c ^ (r & 7);
    GLOAD16(X + (size_t)(mt * 128 + r) * 128 + g * 8, (char*)ldsA + off);
  }
#pragma unroll
  for (int i = 0; i < 4; i++) {
    int off = (w * 4 + i) * 1024 + lane * 16;
    int r = off >> 8, c = (off >> 4) & 15, g = c ^ (r & 7);
    GLOAD16(W + (size_t)(nt * 64 + r) * 128 + g * 8, (char*)ldsB + off);
  }
  __syncthreads();

  const int wm = (w >> 1) * 64, wn = (w & 1) * 32;
  f32x4 zero = {0.f, 0.f, 0.f, 0.f};
  f32x4 acc[4][2];
#pragma unroll
  for (int a = 0; a < 4; a++)
#pragma unroll
    for (int b2 = 0; b2 < 2; b2++) acc[a][b2] = zero;

#pragma unroll
  for (int t = 0; t < 4; t++) {
    bf16x8 af[4], bfr[2];
#pragma unroll
    for (int fm = 0; fm < 4; fm++) {
      int r = wm + fm * 16 + lo;
      int ch = (t * 4 + hi) ^ (r & 7);
      af[fm] = *(const bf16x8*)(ldsA + r * 128 + ch * 8);
    }
#pragma unroll
    for (int fn = 0; fn < 2; fn++) {
      int r = wn + fn * 16 + lo;
      int ch = (t * 4 + hi) ^ (r & 7);
      bfr[fn] = *(const bf16x8*)(ldsB + r * 128 + ch * 8);
    }
#pragma unroll
    for (int fm = 0; fm < 4; fm++)
#pragma unroll
      for (int fn = 0; fn < 2; fn++)
        acc[fm][fn] = MFMA(af[fm], bfr[fn], acc[fm][fn]);
  }

  if (z < 2) {
    u16* dst = z == 0 ? Qh : Kh;
    // Q scale folds 1/sqrt(128) and 1/ln2 (softmax runs in exp2 units)
    const float scale = z == 0 ? 0.12753103392461437f : 1.0f;
#pragma unroll
    for (int fm = 0; fm < 4; fm++)
#pragma unroll
      for (int fn = 0; fn < 2; fn++) {
        int n = nt * 64 + wn + fn * 16 + lo;
        int h = n >> 7, d = n & 127;
#pragma unroll
        for (int j = 0; j < 4; j++) {
          int m = mt * 128 + wm + fm * 16 + hi * 4 + j;
          int b = m >> 11, s = m & 2047;
          dst[(((size_t)(b * 8 + h) * 2048) + s) * 128 + d] =
              f2bf(acc[fm][fn][j] * scale);
        }
      }
  } else {
#pragma unroll
    for (int fm = 0; fm < 4; fm++)
#pragma unroll
      for (int fn = 0; fn < 2; fn++) {
        int n = nt * 64 + wn + fn * 16 + lo;
        int h = n >> 7, d = n & 127;
        int m0 = mt * 128 + wm + fm * 16 + hi * 4;
        int b = m0 >> 11, s0 = m0 & 2047;
        u16x4 pk4;
#pragma unroll
        for (int j = 0; j < 4; j++) pk4[j] = f2bf(acc[fm][fn][j]);
        *(u16x4*)(Vt + ((size_t)(b * 8 + h) * 128 + d) * 2048 + s0) = pk4;
      }
  }
}

// ---------------------------------------------------------------- kattn
// flash attention, 32x32 MFMA, swapped QK^T (T12), in-register softmax,
// tri-buffered K/V with 2-deep counted-vmcnt pipeline (T3/T4), defer-max.
// grid (16 qblocks, 16 bh), 256 thr = 4 waves x 32 q-rows. 1 block/CU.
__global__ __launch_bounds__(256, 1) void kattn(
    const u16* __restrict__ Qh, const u16* __restrict__ Kh,
    const u16* __restrict__ Vt, const u64* __restrict__ pm,
    u16* __restrict__ AO) {
  __shared__ alignas(128) u16 ldsK[3][64 * 128];  // 3 x 16 KB, row = k_local
  __shared__ alignas(128) u16 ldsV[3][128 * 64];  // 3 x 16 KB, row = d
  const int bh = blockIdx.y, b = bh >> 3, h = bh & 7;
  const int tid = threadIdx.x, w = tid >> 6, lane = tid & 63;
  const int lo5 = lane & 31, h5 = lane >> 5;
  const int q0w = blockIdx.x * 128 + w * 32;
  const int q = q0w + lo5;
  const u16* Qb = Qh + (size_t)bh * 2048 * 128;
  const u16* Kb = Kh + (size_t)bh * 2048 * 128;
  const u16* Vb = Vt + (size_t)bh * 128 * 2048;
  const u64* pmb = pm + (size_t)b * 2048 * 32;

#define STAGE(kt, bb)                                                          \
  do {                                                                         \
    const int k0_ = (kt) * 64;                                                 \
    _Pragma("unroll") for (int i = 0; i < 4; i++) {                            \
      int off = (w * 4 + i) * 1024 + lane * 16;                                \
      int r = off >> 8, c = (off >> 4) & 15, g = c ^ (r & 7);                  \
      GLOAD16(Kb + (size_t)(k0_ + r) * 128 + g * 8, (char*)ldsK[bb] + off);    \
    }                                                                          \
    _Pragma("unroll") for (int i = 0; i < 4; i++) {                            \
      int off = (w * 4 + i) * 1024 + lane * 16;                                \
      int d = off >> 7, c = (off >> 4) & 7, g = c ^ (d & 7);                   \
      GLOAD16(Vb + (size_t)d * 2048 + k0_ + g * 8, (char*)ldsV[bb] + off);     \
    }                                                                          \
  } while (0)

  // Q B-frags: B[d][q], lane holds col q = lo5, rows d = ds*16 + h5*8 + j
  bf16x8 qb[8];
#pragma unroll
  for (int ds = 0; ds < 8; ds++)
    qb[ds] = *(const bf16x8*)(Qb + (size_t)q * 128 + ds * 16 + h5 * 8);

  // prologue: pin issue groups with memory-clobber markers so the counted
  // vmcnt(9) below has deterministic FIFO membership (8 stage + 1 mask).
  asm volatile("" ::: "memory");
  STAGE(0, 0);
  u64 mq0 = pmb[(size_t)q * 32 + 0];
  asm volatile("" ::: "memory");
  STAGE(1, 1);
  u64 mq1 = pmb[(size_t)q * 32 + 1];
  asm volatile("s_waitcnt vmcnt(9)" ::: "memory");
  __builtin_amdgcn_sched_barrier(0);
  __builtin_amdgcn_s_barrier();

  f32x16 o0 = Z16, o1 = Z16, o2 = Z16, o3 = Z16;
  float mr = -1e30f, lr = 0.f;

  for (int kt = 0; kt < 32; ++kt) {
    const int bb = kt % 3;
    const u16* Kt = &ldsK[bb][0];
    const u16* Vl = &ldsV[bb][0];
    const u64 mwcur = mq0;
    if (kt + 2 < 32) {
      STAGE(kt + 2, (kt + 2) % 3);
      mq0 = mq1;
      mq1 = pmb[(size_t)q * 32 + kt + 2];
    } else {
      mq0 = mq1;
    }

    // ---- S' = K Q^T: C col = q = lo5, row k = (r&3)+8*(r>>2)+4*h5 (+32*kk)
    f32x16 s0v = Z16, s1v = Z16;
#pragma unroll
    for (int ds = 0; ds < 8; ds++) {
      const int cc = ((ds * 2 + h5) ^ (lo5 & 7)) * 16;
      bf16x8 ka0 = *(const bf16x8*)((const char*)Kt + lo5 * 256 + cc);
      bf16x8 ka1 = *(const bf16x8*)((const char*)Kt + (32 + lo5) * 256 + cc);
      s0v = MFMA32(ka0, qb[ds], s0v);
      s1v = MFMA32(ka1, qb[ds], s1v);
    }

    // ---- row max (unmasked max is exact: scales num+denom identically)
    float tm[16];
#pragma unroll
    for (int r = 0; r < 16; r++) tm[r] = fmaxf(s0v[r], s1v[r]);
#pragma unroll
    for (int st = 8; st > 0; st >>= 1)
#pragma unroll
      for (int r = 0; r < st; r++) tm[r] = fmaxf(tm[r], tm[r + st]);
    float mx = fmaxf(tm[0], __shfl_xor(tm[0], 32));

    // ---- defer-max (T13, THR=8 in exp2 units): rescale only when max grows
    if (__any(mx - mr > 8.0f)) {
      float mn = fmaxf(mr, mx);
      float f = EXP2(mr - mn);
      mr = mn;
      lr *= f;
#pragma unroll
      for (int r = 0; r < 16; r++) {
        const int rowr = (r & 3) + 8 * (r >> 2) + 4 * h5;
        float fr = __shfl(f, rowr);
        o0[r] *= fr; o1[r] *= fr; o2[r] *= fr; o3[r] *= fr;
      }
    }

    // ---- P = exp2(S - m), zeroed by mask bits, + row sum
    const u32 mw0 = (u32)mwcur, mw1 = (u32)(mwcur >> 32);
    float ts[16];
#pragma unroll
    for (int r = 0; r < 16; r++) {
      const int rowr = (r & 3) + 8 * (r >> 2) + 4 * h5;
      float p0 = EXP2(s0v[r] - mr);
      float p1 = EXP2(s1v[r] - mr);
      p0 = ((mw0 >> rowr) & 1u) ? p0 : 0.0f;
      p1 = ((mw1 >> rowr) & 1u) ? p1 : 0.0f;
      s0v[r] = p0;
      s1v[r] = p1;
      ts[r] = p0 + p1;
    }
#pragma unroll
    for (int st = 8; st > 0; st >>= 1)
#pragma unroll
      for (int r = 0; r < st; r++) ts[r] += ts[r + st];
    lr += ts[0] + __shfl_xor(ts[0], 32);

    // ---- P -> bf16 A-frags: cvt_pk pairs + permlane32_swap (T12)
    bf16x8 pa[4];
#pragma unroll
    for (int kk = 0; kk < 2; kk++)
#pragma unroll
      for (int sl = 0; sl < 2; sl++) {
        const int rb = sl * 8;
        u32 W0, W1, W2, W3;
        if (kk == 0) {
          W0 = cvtpk(s0v[rb + 0], s0v[rb + 1]);
          W1 = cvtpk(s0v[rb + 2], s0v[rb + 3]);
          W2 = cvtpk(s0v[rb + 4], s0v[rb + 5]);
          W3 = cvtpk(s0v[rb + 6], s0v[rb + 7]);
        } else {
          W0 = cvtpk(s1v[rb + 0], s1v[rb + 1]);
          W1 = cvtpk(s1v[rb + 2], s1v[rb + 3]);
          W2 = cvtpk(s1v[rb + 4], s1v[rb + 5]);
          W3 = cvtpk(s1v[rb + 6], s1v[rb + 7]);
        }
        plswap(W0, W2);
        plswap(W1, W3);
        u32x4 t = {W0, W1, W2, W3};
        pa[kk * 2 + sl] = __builtin_bit_cast(bf16x8, t);
      }

    // ---- PV: O[q][d] += P A-frag x V B-frag
#pragma unroll
    for (int gsl = 0; gsl < 4; gsl++) {
      const int cc = ((gsl * 2 + h5) ^ (lo5 & 7)) * 16;
      bf16x8 vb0 = *(const bf16x8*)((const char*)Vl + (0 * 32 + lo5) * 128 + cc);
      bf16x8 vb1 = *(const bf16x8*)((const char*)Vl + (1 * 32 + lo5) * 128 + cc);
      bf16x8 vb2 = *(const bf16x8*)((const char*)Vl + (2 * 32 + lo5) * 128 + cc);
      bf16x8 vb3 = *(const bf16x8*)((const char*)Vl + (3 * 32 + lo5) * 128 + cc);
      o0 = MFMA32(pa[gsl], vb0, o0);
      o1 = MFMA32(pa[gsl], vb1, o1);
      o2 = MFMA32(pa[gsl], vb2, o2);
      o3 = MFMA32(pa[gsl], vb3, o3);
    }

    if (kt < 31) {
      if (kt < 30)
        asm volatile("s_waitcnt vmcnt(9)" ::: "memory");
      else
        asm volatile("s_waitcnt vmcnt(0)" ::: "memory");
      __builtin_amdgcn_sched_barrier(0);
      __builtin_amdgcn_s_barrier();
    }
  }
#undef STAGE

  // epilogue: AO[b][q][h*128+d] = O / l  (l redistributed col->row via shfl)
  float linv = 1.0f / lr;
#pragma unroll
  for (int r = 0; r < 16; r++) {
    const int rowr = (r & 3) + 8 * (r >> 2) + 4 * h5;
    float fr = __shfl(linv, rowr);
    const size_t base =
        ((size_t)(b * 2048 + q0w + rowr)) * 1024 + h * 128 + lo5;
    AO[base + 0] = f2bf(o0[r] * fr);
    AO[base + 32] = f2bf(o1[r] * fr);
    AO[base + 64] = f2bf(o2[r] * fr);
    AO[base + 96] = f2bf(o3[r] * fr);
  }
}

// ---------------------------------------------------------------- kout
// AO(4096x1024) @ Wu(128x1024)^T + bu -> fp32 out (4096x128), 2-phase dbuf.
__global__ __launch_bounds__(256) void kout(const u16* __restrict__ AO,
                                            const u16* __restrict__ Wub,
                                            const float* __restrict__ bu,
                                            float* __restrict__ out) {
  __shared__ alignas(128) u16 ldsA[2][64 * 128];    // 2 x 16 KB
  __shared__ alignas(128) u16 ldsW[2][128 * 128];   // 2 x 32 KB
  const int mt = blockIdx.x;
  const int tid = threadIdx.x, w = tid >> 6, lane = tid & 63;
  const int lo = lane & 15, hi = lane >> 4;
  f32x4 zero = {0.f, 0.f, 0.f, 0.f};
  f32x4 acc[8];
#pragma unroll
  for (int fn = 0; fn < 8; fn++) acc[fn] = zero;

#define STAGEO(kb, bb)                                                         \
  do {                                                                         \
    int k0_ = (kb) * 128;                                                      \
    _Pragma("unroll") for (int i = 0; i < 4; i++) {                            \
      int off = (w * 4 + i) * 1024 + lane * 16;                                \
      int r = off >> 8, c = (off >> 4) & 15, g = c ^ (r & 7);                  \
      GLOAD16(AO + (size_t)(mt * 64 + r) * 1024 + k0_ + g * 8,                 \
              (char*)ldsA[bb] + off);                                          \
    }                                                                          \
    _Pragma("unroll") for (int i = 0; i < 8; i++) {                            \
      int off = (w * 8 + i) * 1024 + lane * 16;                                \
      int r = off >> 8, c = (off >> 4) & 15, g = c ^ (r & 7);                  \
      GLOAD16(Wub + (size_t)r * 1024 + k0_ + g * 8, (char*)ldsW[bb] + off);    \
    }                                                                          \
  } while (0)

  STAGEO(0, 0);
  __syncthreads();
  for (int kb = 0; kb < 8; ++kb) {
    const int cb = kb & 1;
    if (kb < 7) STAGEO(kb + 1, cb ^ 1);
    __builtin_amdgcn_s_setprio(1);
#pragma unroll
    for (int t = 0; t < 4; t++) {
      int ra = w * 16 + lo, cha = (t * 4 + hi) ^ (ra & 7);
      bf16x8 af = *(const bf16x8*)(ldsA[cb] + ra * 128 + cha * 8);
#pragma unroll
      for (int fn = 0; fn < 8; fn++) {
        int rb = fn * 16 + lo, chb = (t * 4 + hi) ^ (rb & 7);
        bf16x8 bf_ = *(const bf16x8*)(ldsW[cb] + rb * 128 + chb * 8);
        acc[fn] = MFMA(af, bf_, acc[fn]);
      }
    }
    __builtin_amdgcn_s_setprio(0);
    __syncthreads();
  }
#undef STAGEO

#pragma unroll
  for (int fn = 0; fn < 8; fn++) {
    int n = fn * 16 + lo;
    float bias = bu[n];
#pragma unroll
    for (int j = 0; j < 4; j++) {
      int m = mt * 64 + w * 16 + hi * 4 + j;
      out[(size_t)m * 128 + n] = acc[fn][j] + bias;
    }
  }
}

// ---------------------------------------------------------------- launch
extern "C" void kernel_launch(void* const* d_in, const int* in_sizes, int n_in,
                              void* d_out, int out_size, void* d_ws,
                              size_t ws_size, hipStream_t stream) {
  const float* values = (const float*)d_in[0];
  const float* keys = (const float*)d_in[1];
  const float* query = (const float*)d_in[2];
  const int* mask = (const int*)d_in[3];
  const float* Wv = (const float*)d_in[4];
  const float* Wk = (const float*)d_in[5];
  const float* Wq = (const float*)d_in[6];
  const float* Wu = (const float*)d_in[7];
  const float* bu = (const float*)d_in[8];

  char* ws = (char*)d_ws;
  u16* XV = (u16*)(ws + 0);          // values bf16          1 MB
  u16* XK = (u16*)(ws + 1048576);    // keys bf16
  u16* XQ = (u16*)(ws + 2097152);    // query bf16
  u16* WVB = (u16*)(ws + 3145728);   // weights bf16, 256 KB each
  u16* WKB = (u16*)(ws + 3407872);
  u16* WQB = (u16*)(ws + 3670016);
  u16* WUB = (u16*)(ws + 3932160);
  u16* QH = (u16*)(ws + 4194304);    // (b,h,s,d) scaled     8 MB
  u16* KH = (u16*)(ws + 12582912);   // (b,h,s,d)
  u16* VT = (u16*)(ws + 20971520);   // (b,h,d,s)
  u16* AO = (u16*)(ws + 29360128);   // (b,q,h,d)
  u64* PM = (u64*)(ws + 37748736);   // packed mask          1 MB

  kprep<<<2560, 256, 0, stream>>>(values, keys, query, Wv, Wk, Wq, Wu, mask,
                                  XV, XK, XQ, WVB, WKB, WQB, WUB, PM);
  kproj<<<dim3(32, 16, 3), 256, 0, stream>>>(XQ, XK, XV, WQB, WKB, WVB, QH, KH,
                                             VT);
  kattn<<<dim3(16, 16), 256, 0, stream>>>(QH, KH, VT, PM, AO);
  kout<<<64, 256, 0, stream>>>(AO, WUB, bu, (float*)d_out);
}

// Round 4
// 105.432 us; speedup vs baseline: 1.4836x; 1.2329x over previous
//
#include <hip/hip_runtime.h>

typedef unsigned short u16;
typedef unsigned int u32;
typedef unsigned long long u64;
typedef __attribute__((ext_vector_type(8))) short bf16x8;
typedef __attribute__((ext_vector_type(4))) float f32x4;
typedef __attribute__((ext_vector_type(16))) float f32x16;
typedef __attribute__((ext_vector_type(4))) u32 u32x4;
typedef __attribute__((ext_vector_type(4))) unsigned short u16x4;

// async global->LDS, 16B per lane; LDS dest is wave-uniform base + lane*16
#define GLOAD16(gp, lp)                                                        \
  __builtin_amdgcn_global_load_lds(                                            \
      (__attribute__((address_space(1))) void*)(gp),                           \
      (__attribute__((address_space(3))) void*)(lp), 16, 0, 0)

#if __has_builtin(__builtin_amdgcn_exp2f)
#define EXP2(x) __builtin_amdgcn_exp2f(x)
#else
#define EXP2(x) __expf(0.6931471805599453f * (x))
#endif

#define Z16                                                                    \
  { 0.f, 0.f, 0.f, 0.f, 0.f, 0.f, 0.f, 0.f, 0.f, 0.f, 0.f, 0.f, 0.f, 0.f,     \
    0.f, 0.f }

__device__ __forceinline__ u16 f2bf(float f) {
  u32 u = __builtin_bit_cast(u32, f);
  u += 0x7FFFu + ((u >> 16) & 1u);  // RNE
  return (u16)(u >> 16);
}

__device__ __forceinline__ u32 cvtpk(float lo, float hi) {
  u32 r;
  asm("v_cvt_pk_bf16_f32 %0, %1, %2" : "=v"(r) : "v"(lo), "v"(hi));
  return r;
}

// exchanges a's lanes 32-63 with b's lanes 0-31
__device__ __forceinline__ void plswap(u32& a, u32& b) {
  asm volatile("v_permlane32_swap_b32 %0, %1" : "+v"(a), "+v"(b));
}

__device__ __forceinline__ f32x4 MFMA(bf16x8 a, bf16x8 b, f32x4 c) {
  return __builtin_amdgcn_mfma_f32_16x16x32_bf16(a, b, c, 0, 0, 0);
}
__device__ __forceinline__ f32x16 MFMA32(bf16x8 a, bf16x8 b, f32x16 c) {
  return __builtin_amdgcn_mfma_f32_32x32x16_bf16(a, b, c, 0, 0, 0);
}

// ---------------------------------------------------------------- kprep
// blocks [0,2048): fp32->bf16 convert of v/k/q + 4 weights (float4 granules).
// blocks [2048,2560): bit-pack mask via ballot: 64 ints -> one u64.
__global__ __launch_bounds__(256) void kprep(
    const float* __restrict__ pv, const float* __restrict__ pk,
    const float* __restrict__ pq, const float* __restrict__ pwv,
    const float* __restrict__ pwk, const float* __restrict__ pwq,
    const float* __restrict__ pwu, const int* __restrict__ mask,
    u16* __restrict__ xv, u16* __restrict__ xk, u16* __restrict__ xq,
    u16* __restrict__ wv, u16* __restrict__ wk, u16* __restrict__ wq,
    u16* __restrict__ wu, u64* __restrict__ pm) {
  int blk = blockIdx.x;
  if (blk < 2048) {
    int i = blk * 256 + threadIdx.x;  // float4 index, 524288 total
    const float* src;
    u16* dst;
    int loc;
    if (i < 131072) {            src = pv;  dst = xv; loc = i; }
    else if (i < 262144) {       src = pk;  dst = xk; loc = i - 131072; }
    else if (i < 393216) {       src = pq;  dst = xq; loc = i - 262144; }
    else if (i < 425984) {       src = pwv; dst = wv; loc = i - 393216; }
    else if (i < 458752) {       src = pwk; dst = wk; loc = i - 425984; }
    else if (i < 491520) {       src = pwq; dst = wq; loc = i - 458752; }
    else {                       src = pwu; dst = wu; loc = i - 491520; }
    f32x4 x = *(const f32x4*)(src + (size_t)loc * 4);
    u16x4 o;
    o[0] = f2bf(x[0]); o[1] = f2bf(x[1]); o[2] = f2bf(x[2]); o[3] = f2bf(x[3]);
    *(u16x4*)(dst + (size_t)loc * 4) = o;
  } else {
    int wid = ((blk - 2048) * 256 + threadIdx.x) >> 6;  // 0..2047
    int lane = threadIdx.x & 63;
    for (int it = 0; it < 64; ++it) {
      int word = wid * 64 + it;  // 0..131071
      int x = mask[(size_t)word * 64 + lane];
      u64 bits = __ballot(x != 0);
      if (lane == 0) pm[word] = bits;
    }
  }
}

// ---------------------------------------------------------------- kproj
// X(4096x128) @ W(1024x128)^T, bf16 MFMA. z=0: Q (scaled by 1/(sqrt(128)ln2),
// (b,h,s,d)); z=1: K ((b,h,s,d)); z=2: V transposed ((b,h,d,s)).
__global__ __launch_bounds__(256) void kproj(
    const u16* __restrict__ Xq, const u16* __restrict__ Xk,
    const u16* __restrict__ Xv, const u16* __restrict__ Wqb,
    const u16* __restrict__ Wkb, const u16* __restrict__ Wvb,
    u16* __restrict__ Qh, u16* __restrict__ Kh, u16* __restrict__ Vt) {
  __shared__ alignas(128) u16 ldsA[128 * 128];  // 32 KB
  __shared__ alignas(128) u16 ldsB[64 * 128];   // 16 KB
  const int z = blockIdx.z;
  const u16* X = z == 0 ? Xq : (z == 1 ? Xk : Xv);
  const u16* W = z == 0 ? Wqb : (z == 1 ? Wkb : Wvb);
  const int mt = blockIdx.x, nt = blockIdx.y;
  const int tid = threadIdx.x, w = tid >> 6, lane = tid & 63;
  const int lo = lane & 15, hi = lane >> 4;

#pragma unroll
  for (int i = 0; i < 8; i++) {
    int off = (w * 8 + i) * 1024 + lane * 16;
    int r = off >> 8, c = (off >> 4) & 15, g = c ^ (r & 7);
    GLOAD16(X + (size_t)(mt * 128 + r) * 128 + g * 8, (char*)ldsA + off);
  }
#pragma unroll
  for (int i = 0; i < 4; i++) {
    int off = (w * 4 + i) * 1024 + lane * 16;
    int r = off >> 8, c = (off >> 4) & 15, g = c ^ (r & 7);
    GLOAD16(W + (size_t)(nt * 64 + r) * 128 + g * 8, (char*)ldsB + off);
  }
  __syncthreads();

  const int wm = (w >> 1) * 64, wn = (w & 1) * 32;
  f32x4 zero = {0.f, 0.f, 0.f, 0.f};
  f32x4 acc[4][2];
#pragma unroll
  for (int a = 0; a < 4; a++)
#pragma unroll
    for (int b2 = 0; b2 < 2; b2++) acc[a][b2] = zero;

#pragma unroll
  for (int t = 0; t < 4; t++) {
    bf16x8 af[4], bfr[2];
#pragma unroll
    for (int fm = 0; fm < 4; fm++) {
      int r = wm + fm * 16 + lo;
      int ch = (t * 4 + hi) ^ (r & 7);
      af[fm] = *(const bf16x8*)(ldsA + r * 128 + ch * 8);
    }
#pragma unroll
    for (int fn = 0; fn < 2; fn++) {
      int r = wn + fn * 16 + lo;
      int ch = (t * 4 + hi) ^ (r & 7);
      bfr[fn] = *(const bf16x8*)(ldsB + r * 128 + ch * 8);
    }
#pragma unroll
    for (int fm = 0; fm < 4; fm++)
#pragma unroll
      for (int fn = 0; fn < 2; fn++)
        acc[fm][fn] = MFMA(af[fm], bfr[fn], acc[fm][fn]);
  }

  if (z < 2) {
    u16* dst = z == 0 ? Qh : Kh;
    // Q scale folds 1/sqrt(128) and 1/ln2 (softmax runs in exp2 units)
    const float scale = z == 0 ? 0.12753103392461437f : 1.0f;
#pragma unroll
    for (int fm = 0; fm < 4; fm++)
#pragma unroll
      for (int fn = 0; fn < 2; fn++) {
        int n = nt * 64 + wn + fn * 16 + lo;
        int h = n >> 7, d = n & 127;
#pragma unroll
        for (int j = 0; j < 4; j++) {
          int m = mt * 128 + wm + fm * 16 + hi * 4 + j;
          int b = m >> 11, s = m & 2047;
          dst[(((size_t)(b * 8 + h) * 2048) + s) * 128 + d] =
              f2bf(acc[fm][fn][j] * scale);
        }
      }
  } else {
#pragma unroll
    for (int fm = 0; fm < 4; fm++)
#pragma unroll
      for (int fn = 0; fn < 2; fn++) {
        int n = nt * 64 + wn + fn * 16 + lo;
        int h = n >> 7, d = n & 127;
        int m0 = mt * 128 + wm + fm * 16 + hi * 4;
        int b = m0 >> 11, s0 = m0 & 2047;
        u16x4 pk4;
#pragma unroll
        for (int j = 0; j < 4; j++) pk4[j] = f2bf(acc[fm][fn][j]);
        *(u16x4*)(Vt + ((size_t)(b * 8 + h) * 128 + d) * 2048 + s0) = pk4;
      }
  }
}

// ---------------------------------------------------------------- kattn
// flash attention, 32x32 MFMA, swapped QK^T, in-register softmax (T12),
// defer-max (T13). Split-KV: gridDim.z==2 -> each block does ntiles=16 KV
// tiles of one half, writes self-normalized O + (m,l); kmerge combines.
// Double-buffered LDS (64 KB) + 2 raw barriers + counted vmcnt -> 2 blk/CU.
__global__ __launch_bounds__(256, 2) void kattn(
    const u16* __restrict__ Qh, const u16* __restrict__ Kh,
    const u16* __restrict__ Vt, const u64* __restrict__ pm,
    u16* __restrict__ out0, u16* __restrict__ out1, float2* __restrict__ ML,
    int ntiles) {
  __shared__ alignas(128) u16 ldsK[2][64 * 128];  // 2 x 16 KB, row = k_local
  __shared__ alignas(128) u16 ldsV[2][128 * 64];  // 2 x 16 KB, row = d
  // XCD-grouping decode: all 16 qblk-blocks of one (bh,half) share an XCD L2
  const int F = blockIdx.x + (blockIdx.y << 4) + (blockIdx.z << 8);
  const int two = (gridDim.z == 2) ? 1 : 0;
  const int bh = F & 15;
  const int half = two ? ((F >> 4) & 1) : 0;
  const int qblk = F >> (4 + two);
  const int b = bh >> 3, h = bh & 7;
  const int ktbase = half * ntiles;
  u16* outO = half ? out1 : out0;

  const int tid = threadIdx.x, w = tid >> 6, lane = tid & 63;
  const int lo5 = lane & 31, h5 = lane >> 5;
  const int q0w = qblk * 128 + w * 32;
  const int q = q0w + lo5;
  const u16* Qb = Qh + (size_t)bh * 2048 * 128;
  const u16* Kb = Kh + (size_t)bh * 2048 * 128;
  const u16* Vb = Vt + (size_t)bh * 128 * 2048;
  const u64* pmb = pm + (size_t)b * 2048 * 32;

  // per-lane staging offsets (loop-invariant)
  int kgo[4], vgo[4], slo[4];
#pragma unroll
  for (int i = 0; i < 4; i++) {
    int off = (w * 4 + i) * 1024 + lane * 16;
    slo[i] = off;
    { int r = off >> 8, c = (off >> 4) & 15, gs = c ^ (r & 7);
      kgo[i] = r * 128 + gs * 8; }
    { int d = off >> 7, c = (off >> 4) & 7, gs = c ^ (d & 7);
      vgo[i] = d * 2048 + gs * 8; }
  }
  // per-lane fragment-read offsets (bytes, loop-invariant)
  int kro[8], vro[4];
#pragma unroll
  for (int ds = 0; ds < 8; ds++)
    kro[ds] = lo5 * 256 + (((ds * 2 + h5) ^ (lo5 & 7)) * 16);
#pragma unroll
  for (int g2 = 0; g2 < 4; g2++)
    vro[g2] = lo5 * 128 + (((g2 * 2 + h5) ^ (lo5 & 7)) * 16);

#define STAGE(kt, bb)                                                          \
  do {                                                                         \
    const int k0_ = (kt) * 64;                                                 \
    _Pragma("unroll") for (int i = 0; i < 4; i++)                              \
        GLOAD16(Kb + kgo[i] + (size_t)k0_ * 128,                               \
                (char*)ldsK + (bb) * 16384 + slo[i]);                          \
    _Pragma("unroll") for (int i = 0; i < 4; i++)                              \
        GLOAD16(Vb + vgo[i] + k0_, (char*)ldsV + (bb) * 16384 + slo[i]);       \
  } while (0)

  // Q B-frags: B[d][q], lane holds col q = lo5, rows d = ds*16 + h5*8 + j
  bf16x8 qb[8];
#pragma unroll
  for (int ds = 0; ds < 8; ds++)
    qb[ds] = *(const bf16x8*)(Qb + (size_t)q * 128 + ds * 16 + h5 * 8);

  asm volatile("" ::: "memory");
  STAGE(ktbase, 0);
  asm volatile("" ::: "memory");

  f32x16 o0 = Z16, o1 = Z16, o2 = Z16, o3 = Z16;
  float mr = -1e30f, lr = 0.f;

  for (int t = 0; t < ntiles; ++t) {
    const int bb = t & 1;
    __builtin_amdgcn_s_barrier();  // B_top: tile t-1 readers done everywhere
    u64 mw = pmb[(size_t)q * 32 + ktbase + t];  // 1 vmem (waited at use)
    if (t + 1 < ntiles) {
      STAGE(ktbase + t + 1, bb ^ 1);  // 8 vmem, stays in flight past B_mid
      asm volatile("s_waitcnt vmcnt(9)" ::: "memory");  // own stage(t) done
    } else {
      asm volatile("s_waitcnt vmcnt(1)" ::: "memory");
    }
    __builtin_amdgcn_sched_barrier(0);
    __builtin_amdgcn_s_barrier();  // B_mid: all waves' stage(t) landed
    const char* Kt = (const char*)ldsK + bb * 16384;
    const char* Vl = (const char*)ldsV + bb * 16384;

    // ---- S' = K Q^T: C col = q = lo5, row k = (r&3)+8*(r>>2)+4*h5 (+32*kk)
    f32x16 s0v = Z16, s1v = Z16;
    __builtin_amdgcn_s_setprio(1);
#pragma unroll
    for (int ds = 0; ds < 8; ds++) {
      bf16x8 ka0 = *(const bf16x8*)(Kt + kro[ds]);
      bf16x8 ka1 = *(const bf16x8*)(Kt + kro[ds] + 8192);
      s0v = MFMA32(ka0, qb[ds], s0v);
      s1v = MFMA32(ka1, qb[ds], s1v);
    }
    __builtin_amdgcn_s_setprio(0);

    // ---- row max (unmasked max is exact: scales num+denom identically)
    float tm[16];
#pragma unroll
    for (int r = 0; r < 16; r++) tm[r] = fmaxf(s0v[r], s1v[r]);
#pragma unroll
    for (int st = 8; st > 0; st >>= 1)
#pragma unroll
      for (int r = 0; r < st; r++) tm[r] = fmaxf(tm[r], tm[r + st]);
    float mx = fmaxf(tm[0], __shfl_xor(tm[0], 32));

    // ---- defer-max (T13, THR=8 in exp2 units)
    if (__any(mx - mr > 8.0f)) {
      float mn = fmaxf(mr, mx);
      float f = EXP2(mr - mn);
      mr = mn;
      lr *= f;
#pragma unroll
      for (int r = 0; r < 16; r++) {
        const int rowr = (r & 3) + 8 * (r >> 2) + 4 * h5;
        float fr = __shfl(f, rowr);
        o0[r] *= fr; o1[r] *= fr; o2[r] *= fr; o3[r] *= fr;
      }
    }

    // ---- P = exp2(S - m), zeroed by mask bits, + row sum
    const u32 mw0 = (u32)mw, mw1 = (u32)(mw >> 32);
    float ts[16];
#pragma unroll
    for (int r = 0; r < 16; r++) {
      const int rowr = (r & 3) + 8 * (r >> 2) + 4 * h5;
      float p0 = EXP2(s0v[r] - mr);
      float p1 = EXP2(s1v[r] - mr);
      p0 = ((mw0 >> rowr) & 1u) ? p0 : 0.0f;
      p1 = ((mw1 >> rowr) & 1u) ? p1 : 0.0f;
      s0v[r] = p0;
      s1v[r] = p1;
      ts[r] = p0 + p1;
    }
#pragma unroll
    for (int st = 8; st > 0; st >>= 1)
#pragma unroll
      for (int r = 0; r < st; r++) ts[r] += ts[r + st];
    lr += ts[0] + __shfl_xor(ts[0], 32);

    // ---- P -> bf16 A-frags: cvt_pk pairs + permlane32_swap (T12)
    bf16x8 pa[4];
#pragma unroll
    for (int kk = 0; kk < 2; kk++)
#pragma unroll
      for (int sl = 0; sl < 2; sl++) {
        const int rb = sl * 8;
        u32 W0, W1, W2, W3;
        if (kk == 0) {
          W0 = cvtpk(s0v[rb + 0], s0v[rb + 1]);
          W1 = cvtpk(s0v[rb + 2], s0v[rb + 3]);
          W2 = cvtpk(s0v[rb + 4], s0v[rb + 5]);
          W3 = cvtpk(s0v[rb + 6], s0v[rb + 7]);
        } else {
          W0 = cvtpk(s1v[rb + 0], s1v[rb + 1]);
          W1 = cvtpk(s1v[rb + 2], s1v[rb + 3]);
          W2 = cvtpk(s1v[rb + 4], s1v[rb + 5]);
          W3 = cvtpk(s1v[rb + 6], s1v[rb + 7]);
        }
        plswap(W0, W2);
        plswap(W1, W3);
        u32x4 tt = {W0, W1, W2, W3};
        pa[kk * 2 + sl] = __builtin_bit_cast(bf16x8, tt);
      }

    // ---- PV: O[q][d] += P A-frag x V B-frag
    __builtin_amdgcn_s_setprio(1);
#pragma unroll
    for (int gsl = 0; gsl < 4; gsl++) {
      bf16x8 vb0 = *(const bf16x8*)(Vl + vro[gsl] + 0 * 4096);
      bf16x8 vb1 = *(const bf16x8*)(Vl + vro[gsl] + 1 * 4096);
      bf16x8 vb2 = *(const bf16x8*)(Vl + vro[gsl] + 2 * 4096);
      bf16x8 vb3 = *(const bf16x8*)(Vl + vro[gsl] + 3 * 4096);
      o0 = MFMA32(pa[gsl], vb0, o0);
      o1 = MFMA32(pa[gsl], vb1, o1);
      o2 = MFMA32(pa[gsl], vb2, o2);
      o3 = MFMA32(pa[gsl], vb3, o3);
    }
    __builtin_amdgcn_s_setprio(0);
  }
#undef STAGE

  // epilogue: self-normalized O; (m,l) for split merge
  float linv = lr > 0.f ? 1.0f / lr : 0.f;
#pragma unroll
  for (int r = 0; r < 16; r++) {
    const int rowr = (r & 3) + 8 * (r >> 2) + 4 * h5;
    float fr = __shfl(linv, rowr);
    const size_t base =
        ((size_t)(b * 2048 + q0w + rowr)) * 1024 + h * 128 + lo5;
    outO[base + 0] = f2bf(o0[r] * fr);
    outO[base + 32] = f2bf(o1[r] * fr);
    outO[base + 64] = f2bf(o2[r] * fr);
    outO[base + 96] = f2bf(o3[r] * fr);
  }
  if (two && h5 == 0)
    ML[((size_t)half << 15) + ((size_t)bh << 11) + q] = make_float2(mr, lr);
}

// ---------------------------------------------------------------- kmerge
// AO = merge(OPa with ML[0], OPb with ML[1]); exact flash combine.
// NOTE: OPa may alias AO (elementwise read-then-write by same thread).
__global__ __launch_bounds__(256) void kmerge(const u16* OPa, const u16* OPb,
                                              const float2* __restrict__ ML,
                                              u16* AO) {
  int idx = blockIdx.x * 256 + threadIdx.x;  // 8 bf16 per thread
  int row = idx >> 7, rem = idx & 127, h = rem >> 4;
  int b = row >> 11, q = row & 2047;
  size_t mli = ((size_t)((b << 3) + h) << 11) + q;
  float2 A = ML[mli];
  float2 Bv = ML[32768 + mli];
  float m = fmaxf(A.x, Bv.x);
  float w1 = A.y * EXP2(A.x - m);
  float w2 = Bv.y * EXP2(Bv.x - m);
  float inv = 1.0f / (w1 + w2);
  w1 *= inv;
  w2 *= inv;
  bf16x8 x = *(const bf16x8*)(OPa + (size_t)idx * 8);
  bf16x8 y = *(const bf16x8*)(OPb + (size_t)idx * 8);
  bf16x8 o;
#pragma unroll
  for (int j = 0; j < 8; j++) {
    float xf = __builtin_bit_cast(float, (u32)(u16)x[j] << 16);
    float yf = __builtin_bit_cast(float, (u32)(u16)y[j] << 16);
    o[j] = (short)f2bf(w1 * xf + w2 * yf);
  }
  *(bf16x8*)(AO + (size_t)idx * 8) = o;
}

// ---------------------------------------------------------------- kout
// AO(4096x1024) @ Wu(128x1024)^T + bu -> fp32 out (4096x128), 2-phase dbuf.
__global__ __launch_bounds__(256) void kout(const u16* __restrict__ AO,
                                            const u16* __restrict__ Wub,
                                            const float* __restrict__ bu,
                                            float* __restrict__ out) {
  __shared__ alignas(128) u16 ldsA[2][64 * 128];    // 2 x 16 KB
  __shared__ alignas(128) u16 ldsW[2][128 * 128];   // 2 x 32 KB
  const int mt = blockIdx.x;
  const int tid = threadIdx.x, w = tid >> 6, lane = tid & 63;
  const int lo = lane & 15, hi = lane >> 4;
  f32x4 zero = {0.f, 0.f, 0.f, 0.f};
  f32x4 acc[8];
#pragma unroll
  for (int fn = 0; fn < 8; fn++) acc[fn] = zero;

#define STAGEO(kb, bb)                                                         \
  do {                                                                         \
    int k0_ = (kb) * 128;                                                      \
    _Pragma("unroll") for (int i = 0; i < 4; i++) {                            \
      int off = (w * 4 + i) * 1024 + lane * 16;                                \
      int r = off >> 8, c = (off >> 4) & 15, g = c ^ (r & 7);                  \
      GLOAD16(AO + (size_t)(mt * 64 + r) * 1024 + k0_ + g * 8,                 \
              (char*)ldsA[bb] + off);                                          \
    }                                                                          \
    _Pragma("unroll") for (int i = 0; i < 8; i++) {                            \
      int off = (w * 8 + i) * 1024 + lane * 16;                                \
      int r = off >> 8, c = (off >> 4) & 15, g = c ^ (r & 7);                  \
      GLOAD16(Wub + (size_t)r * 1024 + k0_ + g * 8, (char*)ldsW[bb] + off);    \
    }                                                                          \
  } while (0)

  STAGEO(0, 0);
  __syncthreads();
  for (int kb = 0; kb < 8; ++kb) {
    const int cb = kb & 1;
    if (kb < 7) STAGEO(kb + 1, cb ^ 1);
    __builtin_amdgcn_s_setprio(1);
#pragma unroll
    for (int t = 0; t < 4; t++) {
      int ra = w * 16 + lo, cha = (t * 4 + hi) ^ (ra & 7);
      bf16x8 af = *(const bf16x8*)(ldsA[cb] + ra * 128 + cha * 8);
#pragma unroll
      for (int fn = 0; fn < 8; fn++) {
        int rb = fn * 16 + lo, chb = (t * 4 + hi) ^ (rb & 7);
        bf16x8 bf_ = *(const bf16x8*)(ldsW[cb] + rb * 128 + chb * 8);
        acc[fn] = MFMA(af, bf_, acc[fn]);
      }
    }
    __builtin_amdgcn_s_setprio(0);
    __syncthreads();
  }
#undef STAGEO

#pragma unroll
  for (int fn = 0; fn < 8; fn++) {
    int n = fn * 16 + lo;
    float bias = bu[n];
#pragma unroll
    for (int j = 0; j < 4; j++) {
      int m = mt * 64 + w * 16 + hi * 4 + j;
      out[(size_t)m * 128 + n] = acc[fn][j] + bias;
    }
  }
}

// ---------------------------------------------------------------- launch
extern "C" void kernel_launch(void* const* d_in, const int* in_sizes, int n_in,
                              void* d_out, int out_size, void* d_ws,
                              size_t ws_size, hipStream_t stream) {
  const float* values = (const float*)d_in[0];
  const float* keys = (const float*)d_in[1];
  const float* query = (const float*)d_in[2];
  const int* mask = (const int*)d_in[3];
  const float* Wv = (const float*)d_in[4];
  const float* Wk = (const float*)d_in[5];
  const float* Wq = (const float*)d_in[6];
  const float* Wu = (const float*)d_in[7];
  const float* bu = (const float*)d_in[8];

  char* ws = (char*)d_ws;
  u16* XV = (u16*)(ws + 0);          // values bf16          1 MB
  u16* XK = (u16*)(ws + 1048576);    // keys bf16
  u16* XQ = (u16*)(ws + 2097152);    // query bf16
  u16* WVB = (u16*)(ws + 3145728);   // weights bf16, 256 KB each
  u16* WKB = (u16*)(ws + 3407872);
  u16* WQB = (u16*)(ws + 3670016);
  u16* WUB = (u16*)(ws + 3932160);
  u16* QH = (u16*)(ws + 4194304);    // (b,h,s,d) scaled     8 MB
  u16* KH = (u16*)(ws + 12582912);   // (b,h,s,d)
  u16* VT = (u16*)(ws + 20971520);   // (b,h,d,s)
  u16* AO = (u16*)(ws + 29360128);   // (b,q,h,d) / OP half0 8 MB
  u64* PM = (u64*)(ws + 37748736);   // packed mask          1 MB
  u16* OP1 = (u16*)(ws + 38797312);  // OP half1             8 MB
  float2* MLb = (float2*)(ws + 47185920);  // (m,l) x 2 halves 512 KB
  const size_t NEED = 47710208;

  kprep<<<2560, 256, 0, stream>>>(values, keys, query, Wv, Wk, Wq, Wu, mask,
                                  XV, XK, XQ, WVB, WKB, WQB, WUB, PM);
  kproj<<<dim3(32, 16, 3), 256, 0, stream>>>(XQ, XK, XV, WQB, WKB, WVB, QH, KH,
                                             VT);
  if (ws_size >= NEED) {
    kattn<<<dim3(16, 16, 2), 256, 0, stream>>>(QH, KH, VT, PM, AO, OP1, MLb,
                                               16);
    kmerge<<<2048, 256, 0, stream>>>(AO, OP1, MLb, AO);
  } else {
    kattn<<<dim3(16, 16, 1), 256, 0, stream>>>(QH, KH, VT, PM, AO, AO, MLb,
                                               32);
  }
  kout<<<64, 256, 0, stream>>>(AO, WUB, bu, (float*)d_out);
}

// Round 5
// 99.653 us; speedup vs baseline: 1.5697x; 1.0580x over previous
//
#include <hip/hip_runtime.h>

typedef unsigned short u16;
typedef unsigned int u32;
typedef unsigned long long u64;
typedef __attribute__((ext_vector_type(8))) short bf16x8;
typedef __attribute__((ext_vector_type(4))) float f32x4;
typedef __attribute__((ext_vector_type(16))) float f32x16;
typedef __attribute__((ext_vector_type(4))) u32 u32x4;

// async global->LDS, 16B per lane; LDS dest is wave-uniform base + lane*16
#define GLOAD16(gp, lp)                                                        \
  __builtin_amdgcn_global_load_lds(                                            \
      (__attribute__((address_space(1))) void*)(gp),                           \
      (__attribute__((address_space(3))) void*)(lp), 16, 0, 0)

#if __has_builtin(__builtin_amdgcn_exp2f)
#define EXP2(x) __builtin_amdgcn_exp2f(x)
#else
#define EXP2(x) __expf(0.6931471805599453f * (x))
#endif

#define Z16                                                                    \
  { 0.f, 0.f, 0.f, 0.f, 0.f, 0.f, 0.f, 0.f, 0.f, 0.f, 0.f, 0.f, 0.f, 0.f,     \
    0.f, 0.f }

__device__ __forceinline__ u16 f2bf(float f) {
  u32 u = __builtin_bit_cast(u32, f);
  u += 0x7FFFu + ((u >> 16) & 1u);  // RNE
  return (u16)(u >> 16);
}

__device__ __forceinline__ float bf2f(short s) {
  return __builtin_bit_cast(float, (u32)(u16)s << 16);
}

__device__ __forceinline__ u32 cvtpk(float lo, float hi) {
  u32 r;
  asm("v_cvt_pk_bf16_f32 %0, %1, %2" : "=v"(r) : "v"(lo), "v"(hi));
  return r;
}

// exchanges a's lanes 32-63 with b's lanes 0-31
__device__ __forceinline__ void plswap(u32& a, u32& b) {
  asm volatile("v_permlane32_swap_b32 %0, %1" : "+v"(a), "+v"(b));
}

__device__ __forceinline__ f32x4 MFMA(bf16x8 a, bf16x8 b, f32x4 c) {
  return __builtin_amdgcn_mfma_f32_16x16x32_bf16(a, b, c, 0, 0, 0);
}
__device__ __forceinline__ f32x16 MFMA32(bf16x8 a, bf16x8 b, f32x16 c) {
  return __builtin_amdgcn_mfma_f32_32x32x16_bf16(a, b, c, 0, 0, 0);
}

// convert 8 fp32 (2x f32x4) -> one 16B bf16 chunk
__device__ __forceinline__ u32x4 cvt8(f32x4 a, f32x4 b) {
  u32x4 o;
  o[0] = cvtpk(a[0], a[1]);
  o[1] = cvtpk(a[2], a[3]);
  o[2] = cvtpk(b[0], b[1]);
  o[3] = cvtpk(b[2], b[3]);
  return o;
}

// ---------------------------------------------------------------- kmaskbias
// blocks [0,512): bit-pack mask via ballot: 64 ints -> one u64.
// blocks [512,544): prefill out with bias (atomic split-K accumulates onto it)
__global__ __launch_bounds__(256) void kmaskbias(const int* __restrict__ mask,
                                                 const float* __restrict__ bu,
                                                 u64* __restrict__ pm,
                                                 float* __restrict__ out) {
  int blk = blockIdx.x;
  if (blk < 512) {
    int wid = (blk * 256 + threadIdx.x) >> 6;  // 0..2047
    int lane = threadIdx.x & 63;
    for (int it = 0; it < 64; ++it) {
      int word = wid * 64 + it;  // 0..131071
      int x = mask[(size_t)word * 64 + lane];
      u64 bits = __ballot(x != 0);
      if (lane == 0) pm[word] = bits;
    }
  } else {
    int b2 = blk - 512;  // 0..31
    for (int it = 0; it < 16; ++it) {
      int idx = (it * 32 + b2) * 256 + threadIdx.x;  // f32x4 idx, 131072 total
      int n0 = (idx * 4) & 127;
      f32x4 bv = *(const f32x4*)(bu + n0);
      *((f32x4*)out + idx) = bv;
    }
  }
}

// ---------------------------------------------------------------- kproj
// X(4096x128 fp32) @ W(1024x128 fp32)^T, bf16 MFMA; converts fp32->bf16
// during reg-staged LDS fill. z=0: Q (scaled by 1/(sqrt(128)ln2), (b,h,s,d));
// z=1: K ((b,h,s,d)); z=2: V transposed ((b,h,d,s)).
__global__ __launch_bounds__(256) void kproj(
    const float* __restrict__ Xq, const float* __restrict__ Xk,
    const float* __restrict__ Xv, const float* __restrict__ Wqf,
    const float* __restrict__ Wkf, const float* __restrict__ Wvf,
    u16* __restrict__ Qh, u16* __restrict__ Kh, u16* __restrict__ Vt) {
  __shared__ alignas(128) u16 ldsA[128 * 128];  // 32 KB
  __shared__ alignas(128) u16 ldsB[64 * 128];   // 16 KB
  const int z = blockIdx.z;
  const float* X = z == 0 ? Xq : (z == 1 ? Xk : Xv);
  const float* W = z == 0 ? Wqf : (z == 1 ? Wkf : Wvf);
  const int mt = blockIdx.x, nt = blockIdx.y;
  const int tid = threadIdx.x, w = tid >> 6, lane = tid & 63;
  const int lo = lane & 15, hi = lane >> 4;

  // stage A: 128 rows x 16 chunks; LDS[r][c^(r&7)] = X[r][c] (bf16)
#pragma unroll
  for (int i = 0; i < 8; i++) {
    int cid = i * 256 + tid;
    int r = cid >> 4, c = cid & 15;
    const float* src = X + (size_t)(mt * 128 + r) * 128 + c * 8;
    f32x4 a = *(const f32x4*)src;
    f32x4 b = *(const f32x4*)(src + 4);
    *(u32x4*)(ldsA + r * 128 + (c ^ (r & 7)) * 8) = cvt8(a, b);
  }
  // stage B: 64 rows x 16 chunks
#pragma unroll
  for (int i = 0; i < 4; i++) {
    int cid = i * 256 + tid;
    int r = cid >> 4, c = cid & 15;
    const float* src = W + (size_t)(nt * 64 + r) * 128 + c * 8;
    f32x4 a = *(const f32x4*)src;
    f32x4 b = *(const f32x4*)(src + 4);
    *(u32x4*)(ldsB + r * 128 + (c ^ (r & 7)) * 8) = cvt8(a, b);
  }
  __syncthreads();

  const int wm = (w >> 1) * 64, wn = (w & 1) * 32;
  f32x4 zero = {0.f, 0.f, 0.f, 0.f};
  f32x4 acc[4][2];
#pragma unroll
  for (int a = 0; a < 4; a++)
#pragma unroll
    for (int b2 = 0; b2 < 2; b2++) acc[a][b2] = zero;

#pragma unroll
  for (int t = 0; t < 4; t++) {
    bf16x8 af[4], bfr[2];
#pragma unroll
    for (int fm = 0; fm < 4; fm++) {
      int r = wm + fm * 16 + lo;
      int ch = (t * 4 + hi) ^ (r & 7);
      af[fm] = *(const bf16x8*)(ldsA + r * 128 + ch * 8);
    }
#pragma unroll
    for (int fn = 0; fn < 2; fn++) {
      int r = wn + fn * 16 + lo;
      int ch = (t * 4 + hi) ^ (r & 7);
      bfr[fn] = *(const bf16x8*)(ldsB + r * 128 + ch * 8);
    }
#pragma unroll
    for (int fm = 0; fm < 4; fm++)
#pragma unroll
      for (int fn = 0; fn < 2; fn++)
        acc[fm][fn] = MFMA(af[fm], bfr[fn], acc[fm][fn]);
  }

  if (z < 2) {
    u16* dst = z == 0 ? Qh : Kh;
    // Q scale folds 1/sqrt(128) and 1/ln2 (softmax runs in exp2 units)
    const float scale = z == 0 ? 0.12753103392461437f : 1.0f;
#pragma unroll
    for (int fm = 0; fm < 4; fm++)
#pragma unroll
      for (int fn = 0; fn < 2; fn++) {
        int n = nt * 64 + wn + fn * 16 + lo;
        int h = n >> 7, d = n & 127;
#pragma unroll
        for (int j = 0; j < 4; j++) {
          int m = mt * 128 + wm + fm * 16 + hi * 4 + j;
          int b = m >> 11, s = m & 2047;
          dst[(((size_t)(b * 8 + h) * 2048) + s) * 128 + d] =
              f2bf(acc[fm][fn][j] * scale);
        }
      }
  } else {
    typedef __attribute__((ext_vector_type(4))) u16 u16x4t;
#pragma unroll
    for (int fm = 0; fm < 4; fm++)
#pragma unroll
      for (int fn = 0; fn < 2; fn++) {
        int n = nt * 64 + wn + fn * 16 + lo;
        int h = n >> 7, d = n & 127;
        int m0 = mt * 128 + wm + fm * 16 + hi * 4;
        int b = m0 >> 11, s0 = m0 & 2047;
        u16x4t pk4;
#pragma unroll
        for (int j = 0; j < 4; j++) pk4[j] = f2bf(acc[fm][fn][j]);
        *(u16x4t*)(Vt + ((size_t)(b * 8 + h) * 128 + d) * 2048 + s0) = pk4;
      }
  }
}

// ---------------------------------------------------------------- kattn
// flash attention, 32x32 MFMA, swapped QK^T, in-register softmax (T12),
// defer-max (T13). Split-KV: gridDim.z==2 -> each block does ntiles=16 KV
// tiles of one half, writes self-normalized O + (m,l); kout merges.
// Double-buffered LDS (64 KB) + 2 raw barriers + counted vmcnt -> 2 blk/CU.
__global__ __launch_bounds__(256, 2) void kattn(
    const u16* __restrict__ Qh, const u16* __restrict__ Kh,
    const u16* __restrict__ Vt, const u64* __restrict__ pm,
    u16* __restrict__ out0, u16* __restrict__ out1, float2* __restrict__ ML,
    int ntiles) {
  __shared__ alignas(128) u16 ldsK[2][64 * 128];  // 2 x 16 KB, row = k_local
  __shared__ alignas(128) u16 ldsV[2][128 * 64];  // 2 x 16 KB, row = d
  // XCD-grouping decode: all 16 qblk-blocks of one (bh,half) share an XCD L2
  const int F = blockIdx.x + (blockIdx.y << 4) + (blockIdx.z << 8);
  const int two = (gridDim.z == 2) ? 1 : 0;
  const int bh = F & 15;
  const int half = two ? ((F >> 4) & 1) : 0;
  const int qblk = F >> (4 + two);
  const int b = bh >> 3, h = bh & 7;
  const int ktbase = half * ntiles;
  u16* outO = half ? out1 : out0;

  const int tid = threadIdx.x, w = tid >> 6, lane = tid & 63;
  const int lo5 = lane & 31, h5 = lane >> 5;
  const int q0w = qblk * 128 + w * 32;
  const int q = q0w + lo5;
  const u16* Qb = Qh + (size_t)bh * 2048 * 128;
  const u16* Kb = Kh + (size_t)bh * 2048 * 128;
  const u16* Vb = Vt + (size_t)bh * 128 * 2048;
  const u64* pmb = pm + (size_t)b * 2048 * 32;

  // per-lane staging offsets (loop-invariant)
  int kgo[4], vgo[4], slo[4];
#pragma unroll
  for (int i = 0; i < 4; i++) {
    int off = (w * 4 + i) * 1024 + lane * 16;
    slo[i] = off;
    { int r = off >> 8, c = (off >> 4) & 15, gs = c ^ (r & 7);
      kgo[i] = r * 128 + gs * 8; }
    { int d = off >> 7, c = (off >> 4) & 7, gs = c ^ (d & 7);
      vgo[i] = d * 2048 + gs * 8; }
  }
  // per-lane fragment-read offsets (bytes, loop-invariant)
  int kro[8], vro[4];
#pragma unroll
  for (int ds = 0; ds < 8; ds++)
    kro[ds] = lo5 * 256 + (((ds * 2 + h5) ^ (lo5 & 7)) * 16);
#pragma unroll
  for (int g2 = 0; g2 < 4; g2++)
    vro[g2] = lo5 * 128 + (((g2 * 2 + h5) ^ (lo5 & 7)) * 16);

#define STAGE(kt, bb)                                                          \
  do {                                                                         \
    const int k0_ = (kt) * 64;                                                 \
    _Pragma("unroll") for (int i = 0; i < 4; i++)                              \
        GLOAD16(Kb + kgo[i] + (size_t)k0_ * 128,                               \
                (char*)ldsK + (bb) * 16384 + slo[i]);                          \
    _Pragma("unroll") for (int i = 0; i < 4; i++)                              \
        GLOAD16(Vb + vgo[i] + k0_, (char*)ldsV + (bb) * 16384 + slo[i]);       \
  } while (0)

  // Q B-frags: B[d][q], lane holds col q = lo5, rows d = ds*16 + h5*8 + j
  bf16x8 qb[8];
#pragma unroll
  for (int ds = 0; ds < 8; ds++)
    qb[ds] = *(const bf16x8*)(Qb + (size_t)q * 128 + ds * 16 + h5 * 8);

  asm volatile("" ::: "memory");
  STAGE(ktbase, 0);
  asm volatile("" ::: "memory");

  f32x16 o0 = Z16, o1 = Z16, o2 = Z16, o3 = Z16;
  float mr = -1e30f, lr = 0.f;

  for (int t = 0; t < ntiles; ++t) {
    const int bb = t & 1;
    __builtin_amdgcn_s_barrier();  // B_top: tile t-1 readers done everywhere
    u64 mw = pmb[(size_t)q * 32 + ktbase + t];  // 1 vmem (waited at use)
    if (t + 1 < ntiles) {
      STAGE(ktbase + t + 1, bb ^ 1);  // 8 vmem, stays in flight past B_mid
      asm volatile("s_waitcnt vmcnt(9)" ::: "memory");  // own stage(t) done
    } else {
      asm volatile("s_waitcnt vmcnt(1)" ::: "memory");
    }
    __builtin_amdgcn_sched_barrier(0);
    __builtin_amdgcn_s_barrier();  // B_mid: all waves' stage(t) landed
    const char* Kt = (const char*)ldsK + bb * 16384;
    const char* Vl = (const char*)ldsV + bb * 16384;

    // ---- S' = K Q^T: C col = q = lo5, row k = (r&3)+8*(r>>2)+4*h5 (+32*kk)
    f32x16 s0v = Z16, s1v = Z16;
    __builtin_amdgcn_s_setprio(1);
#pragma unroll
    for (int ds = 0; ds < 8; ds++) {
      bf16x8 ka0 = *(const bf16x8*)(Kt + kro[ds]);
      bf16x8 ka1 = *(const bf16x8*)(Kt + kro[ds] + 8192);
      s0v = MFMA32(ka0, qb[ds], s0v);
      s1v = MFMA32(ka1, qb[ds], s1v);
    }
    __builtin_amdgcn_s_setprio(0);

    // ---- row max (unmasked max is exact: scales num+denom identically)
    float tm[16];
#pragma unroll
    for (int r = 0; r < 16; r++) tm[r] = fmaxf(s0v[r], s1v[r]);
#pragma unroll
    for (int st = 8; st > 0; st >>= 1)
#pragma unroll
      for (int r = 0; r < st; r++) tm[r] = fmaxf(tm[r], tm[r + st]);
    float mx = fmaxf(tm[0], __shfl_xor(tm[0], 32));

    // ---- defer-max (T13, THR=8 in exp2 units)
    if (__any(mx - mr > 8.0f)) {
      float mn = fmaxf(mr, mx);
      float f = EXP2(mr - mn);
      mr = mn;
      lr *= f;
#pragma unroll
      for (int r = 0; r < 16; r++) {
        const int rowr = (r & 3) + 8 * (r >> 2) + 4 * h5;
        float fr = __shfl(f, rowr);
        o0[r] *= fr; o1[r] *= fr; o2[r] *= fr; o3[r] *= fr;
      }
    }

    // ---- P = exp2(S - m), zeroed by mask bits, + row sum
    const u32 mw0 = (u32)mw, mw1 = (u32)(mw >> 32);
    float ts[16];
#pragma unroll
    for (int r = 0; r < 16; r++) {
      const int rowr = (r & 3) + 8 * (r >> 2) + 4 * h5;
      float p0 = EXP2(s0v[r] - mr);
      float p1 = EXP2(s1v[r] - mr);
      p0 = ((mw0 >> rowr) & 1u) ? p0 : 0.0f;
      p1 = ((mw1 >> rowr) & 1u) ? p1 : 0.0f;
      s0v[r] = p0;
      s1v[r] = p1;
      ts[r] = p0 + p1;
    }
#pragma unroll
    for (int st = 8; st > 0; st >>= 1)
#pragma unroll
      for (int r = 0; r < st; r++) ts[r] += ts[r + st];
    lr += ts[0] + __shfl_xor(ts[0], 32);

    // ---- P -> bf16 A-frags: cvt_pk pairs + permlane32_swap (T12)
    bf16x8 pa[4];
#pragma unroll
    for (int kk = 0; kk < 2; kk++)
#pragma unroll
      for (int sl = 0; sl < 2; sl++) {
        const int rb = sl * 8;
        u32 W0, W1, W2, W3;
        if (kk == 0) {
          W0 = cvtpk(s0v[rb + 0], s0v[rb + 1]);
          W1 = cvtpk(s0v[rb + 2], s0v[rb + 3]);
          W2 = cvtpk(s0v[rb + 4], s0v[rb + 5]);
          W3 = cvtpk(s0v[rb + 6], s0v[rb + 7]);
        } else {
          W0 = cvtpk(s1v[rb + 0], s1v[rb + 1]);
          W1 = cvtpk(s1v[rb + 2], s1v[rb + 3]);
          W2 = cvtpk(s1v[rb + 4], s1v[rb + 5]);
          W3 = cvtpk(s1v[rb + 6], s1v[rb + 7]);
        }
        plswap(W0, W2);
        plswap(W1, W3);
        u32x4 tt = {W0, W1, W2, W3};
        pa[kk * 2 + sl] = __builtin_bit_cast(bf16x8, tt);
      }

    // ---- PV: O[q][d] += P A-frag x V B-frag
    __builtin_amdgcn_s_setprio(1);
#pragma unroll
    for (int gsl = 0; gsl < 4; gsl++) {
      bf16x8 vb0 = *(const bf16x8*)(Vl + vro[gsl] + 0 * 4096);
      bf16x8 vb1 = *(const bf16x8*)(Vl + vro[gsl] + 1 * 4096);
      bf16x8 vb2 = *(const bf16x8*)(Vl + vro[gsl] + 2 * 4096);
      bf16x8 vb3 = *(const bf16x8*)(Vl + vro[gsl] + 3 * 4096);
      o0 = MFMA32(pa[gsl], vb0, o0);
      o1 = MFMA32(pa[gsl], vb1, o1);
      o2 = MFMA32(pa[gsl], vb2, o2);
      o3 = MFMA32(pa[gsl], vb3, o3);
    }
    __builtin_amdgcn_s_setprio(0);
  }
#undef STAGE

  // epilogue: self-normalized O; (m,l) for split merge
  float linv = lr > 0.f ? 1.0f / lr : 0.f;
#pragma unroll
  for (int r = 0; r < 16; r++) {
    const int rowr = (r & 3) + 8 * (r >> 2) + 4 * h5;
    float fr = __shfl(linv, rowr);
    const size_t base =
        ((size_t)(b * 2048 + q0w + rowr)) * 1024 + h * 128 + lo5;
    outO[base + 0] = f2bf(o0[r] * fr);
    outO[base + 32] = f2bf(o1[r] * fr);
    outO[base + 64] = f2bf(o2[r] * fr);
    outO[base + 96] = f2bf(o3[r] * fr);
  }
  if (two && h5 == 0)
    ML[((size_t)half << 15) + ((size_t)bh << 11) + q] = make_float2(mr, lr);
}

// ---------------------------------------------------------------- koutf
// out += merge(OP0,OP1; ML) @ Wu^T, split-K x4 with fp32 HW atomics.
// K-chunk of 128 == one head, so merge weights are per-row constants.
// Wu read as fp32 and converted during staging. out pre-filled with bias.
__global__ __launch_bounds__(256) void koutf(
    const u16* __restrict__ OP0, const u16* __restrict__ OP1,
    const float2* __restrict__ ML, const float* __restrict__ Wuf,
    float* __restrict__ out, int nsplit) {
  __shared__ alignas(128) u16 ldsA[64 * 128];    // 16 KB
  __shared__ alignas(128) u16 ldsW[128 * 128];   // 32 KB
  const int mt = blockIdx.x;  // 0..63
  const int kc = blockIdx.y;  // 0..3
  const int tid = threadIdx.x, w = tid >> 6, lane = tid & 63;
  const int lo = lane & 15, hi = lane >> 4;
  f32x4 zero = {0.f, 0.f, 0.f, 0.f};
  f32x4 acc[8];
#pragma unroll
  for (int fn = 0; fn < 8; fn++) acc[fn] = zero;

  for (int ks = 0; ks < 2; ++ks) {
    const int h = kc * 2 + ks;
    const int k0 = h * 128;
    // stage A (64 rows x 16 chunks) with fused flash-combine
#pragma unroll
    for (int i = 0; i < 4; i++) {
      int cid = i * 256 + tid;
      int r = cid >> 4, c = cid & 15;
      int m = mt * 64 + r, b = m >> 11, q = m & 2047;
      size_t off = (size_t)m * 1024 + k0 + c * 8;
      bf16x8 x = *(const bf16x8*)(OP0 + off);
      u32x4 ow;
      if (nsplit == 2) {
        bf16x8 y = *(const bf16x8*)(OP1 + off);
        size_t mli = (((size_t)(b << 3) + h) << 11) + q;
        float2 A = ML[mli];
        float2 Bv = ML[32768 + mli];
        float mm = fmaxf(A.x, Bv.x);
        float w1 = A.y * EXP2(A.x - mm);
        float w2 = Bv.y * EXP2(Bv.x - mm);
        float inv = 1.0f / (w1 + w2);
        w1 *= inv;
        w2 *= inv;
        float f[8];
#pragma unroll
        for (int j = 0; j < 8; j++) f[j] = w1 * bf2f(x[j]) + w2 * bf2f(y[j]);
        ow[0] = cvtpk(f[0], f[1]);
        ow[1] = cvtpk(f[2], f[3]);
        ow[2] = cvtpk(f[4], f[5]);
        ow[3] = cvtpk(f[6], f[7]);
      } else {
        ow = __builtin_bit_cast(u32x4, x);
      }
      *(u32x4*)(ldsA + r * 128 + (c ^ (r & 7)) * 8) = ow;
    }
    // stage W (128 rows x 16 chunks) fp32 -> bf16
#pragma unroll
    for (int i = 0; i < 8; i++) {
      int cid = i * 256 + tid;
      int r = cid >> 4, c = cid & 15;
      const float* src = Wuf + (size_t)r * 1024 + k0 + c * 8;
      f32x4 a = *(const f32x4*)src;
      f32x4 bq = *(const f32x4*)(src + 4);
      *(u32x4*)(ldsW + r * 128 + (c ^ (r & 7)) * 8) = cvt8(a, bq);
    }
    __syncthreads();
    __builtin_amdgcn_s_setprio(1);
#pragma unroll
    for (int t = 0; t < 4; t++) {
      int ra = w * 16 + lo, cha = (t * 4 + hi) ^ (ra & 7);
      bf16x8 af = *(const bf16x8*)(ldsA + ra * 128 + cha * 8);
#pragma unroll
      for (int fn = 0; fn < 8; fn++) {
        int rb = fn * 16 + lo, chb = (t * 4 + hi) ^ (rb & 7);
        bf16x8 bf_ = *(const bf16x8*)(ldsW + rb * 128 + chb * 8);
        acc[fn] = MFMA(af, bf_, acc[fn]);
      }
    }
    __builtin_amdgcn_s_setprio(0);
    __syncthreads();
  }

#pragma unroll
  for (int fn = 0; fn < 8; fn++) {
    int n = fn * 16 + lo;
#pragma unroll
    for (int j = 0; j < 4; j++) {
      int m = mt * 64 + w * 16 + hi * 4 + j;
      unsafeAtomicAdd(&out[(size_t)m * 128 + n], acc[fn][j]);
    }
  }
}

// ---------------------------------------------------------------- launch
extern "C" void kernel_launch(void* const* d_in, const int* in_sizes, int n_in,
                              void* d_out, int out_size, void* d_ws,
                              size_t ws_size, hipStream_t stream) {
  const float* values = (const float*)d_in[0];
  const float* keys = (const float*)d_in[1];
  const float* query = (const float*)d_in[2];
  const int* mask = (const int*)d_in[3];
  const float* Wv = (const float*)d_in[4];
  const float* Wk = (const float*)d_in[5];
  const float* Wq = (const float*)d_in[6];
  const float* Wu = (const float*)d_in[7];
  const float* bu = (const float*)d_in[8];

  char* ws = (char*)d_ws;
  u16* QH = (u16*)(ws + 0);           // (b,h,s,d) scaled    8 MB
  u16* KH = (u16*)(ws + 8388608);     // (b,h,s,d)           8 MB
  u16* VT = (u16*)(ws + 16777216);    // (b,h,d,s)           8 MB
  u16* OP0 = (u16*)(ws + 25165824);   // O half0 (b,q,h*d)   8 MB
  u16* OP1 = (u16*)(ws + 33554432);   // O half1             8 MB
  u64* PM = (u64*)(ws + 41943040);    // packed mask         1 MB
  float2* MLb = (float2*)(ws + 42991616);  // (m,l) x 2     512 KB
  const size_t NEED = 43515904;

  float* out = (float*)d_out;
  kmaskbias<<<544, 256, 0, stream>>>(mask, bu, PM, out);
  kproj<<<dim3(32, 16, 3), 256, 0, stream>>>(query, keys, values, Wq, Wk, Wv,
                                             QH, KH, VT);
  if (ws_size >= NEED) {
    kattn<<<dim3(16, 16, 2), 256, 0, stream>>>(QH, KH, VT, PM, OP0, OP1, MLb,
                                               16);
    koutf<<<dim3(64, 4), 256, 0, stream>>>(OP0, OP1, MLb, Wu, out, 2);
  } else {
    kattn<<<dim3(16, 16, 1), 256, 0, stream>>>(QH, KH, VT, PM, OP0, OP0, MLb,
                                               32);
    koutf<<<dim3(64, 4), 256, 0, stream>>>(OP0, OP0, MLb, Wu, out, 1);
  }
}